// Round 8
// baseline (124.772 us; speedup 1.0000x reference)
//
#include <hip/hip_runtime.h>

typedef unsigned short u16;
typedef __attribute__((ext_vector_type(8))) short bf16x8;
typedef __attribute__((ext_vector_type(4))) float f32x4;

#define LSTR 520  // bf16 elems per LDS row: 512 + 8 pad

// ---------------- workspace layout (bytes) ----------------
#define WS_ACT     0          // 512x512 bf16 activations (524288 B)
#define WS_A0V     524288
#define WS_A0O     1048576
#define WS_QW      1572864
#define WS_QKV     2097152
#define WS_QUE     2621440
#define WS_A1V     3145728
#define WS_A1O     3670016
#define WS_VAL     4194304
#define WS_POL     4718592
#define WS_PWR     7882752
#define WS_KK      7915520
#define WS_VV      7981056
#define WS_A0VB    8574976
#define WS_A0OB    (WS_A0VB + 1024)
#define WS_QB      (WS_A0VB + 2048)
#define WS_QKVB    (WS_A0VB + 5120)
#define WS_QUEB    (WS_A0VB + 6144)
#define WS_A1VB    (WS_A0VB + 7168)
#define WS_A1OB    (WS_A0VB + 8192)
#define WS_VALB    (WS_A0VB + 9216)
#define WS_ANG     (WS_A0VB + 10240)
#define WS_ANB     (WS_A0VB + 11264)
#define WS_FNG     (WS_A0VB + 12288)
#define WS_FNB     (WS_A0VB + 13312)
#define WS_POLB    (WS_A0VB + 14336)
#define WS_CTR     8650752    // grid-barrier counter (4 B), memset to 0 each launch

__device__ __forceinline__ float bf2f(u16 u) {
  union { unsigned int i; float f; } v; v.i = ((unsigned int)u) << 16; return v.f;
}
__device__ __forceinline__ u16 f2bf(float f) {
  union { float f; unsigned int i; } v; v.f = f;
  unsigned int r = v.i + 0x7fffu + ((v.i >> 16) & 1u);
  return (u16)(r >> 16);
}
__device__ __forceinline__ bf16x8 f8_to_bf(const float4 a, const float4 b) {
  u16 o[8] = {f2bf(a.x), f2bf(a.y), f2bf(a.z), f2bf(a.w),
              f2bf(b.x), f2bf(b.y), f2bf(b.z), f2bf(b.w)};
  return *(bf16x8*)o;
}
__device__ __forceinline__ f32x4 MFMA(bf16x8 a, bf16x8 b, f32x4 c) {
  return __builtin_amdgcn_mfma_f32_16x16x32_bf16(a, b, c, 0, 0, 0);
}
__device__ __forceinline__ void gl_lds16(const void* g, void* l) {
  __builtin_amdgcn_global_load_lds((const __attribute__((address_space(1))) void*)g,
                                   (__attribute__((address_space(3))) void*)l, 16, 0, 0);
}

// ---- device-wide barrier (128 blocks co-resident; monotonic phase targets).
// Release: per-wave vmcnt(0) (stores done; also drains DMA - acceptable),
// tid0 __threadfence (L2 writeback) + atomicAdd. Acquire: spin + __threadfence
// (L1/L2 invalidate) + __syncthreads. Bounded spin: fail loud, not hang.
__device__ __forceinline__ void gridbar(int* ctr, int target, int tid) {
  asm volatile("s_waitcnt vmcnt(0)" ::: "memory");
  __syncthreads();
  if (tid == 0) {
    __threadfence();
    atomicAdd(ctr, 1);
    int it = 0;
    while (atomicAdd(ctr, 0) < target) { if (++it > 300000000) break; }
    __threadfence();
  }
  __syncthreads();
}

// ---------------- convert jobs (phase 0 of k_main, 128 slices) ----------------
// mode 0: plain f32->bf16. mode 1: per-32col-slice chunked for 512x512 W:
// elem (col,k): dst = (col>>5)*16384 + (k>>5)*1024 + ((k>>3)&3)*256 + (col&31)*8 + (k&7)
#define NJOBS 22
struct Job { const void* base; int eoff; int n; int dstoff; int mode; };
struct Jobs { Job j[NJOBS]; };

__device__ void conv_part(const Jobs& jobs, char* __restrict__ ws, int slice, int nslice) {
  const int tid = threadIdx.x;
  for (int jj = 0; jj < NJOBS; ++jj) {
    const Job jb = jobs.j[jj];
    u16* dst = (u16*)(ws + jb.dstoff);
    const float* src = (const float*)jb.base + jb.eoff;
    const int items = (jb.n + 7) >> 3;
    const int per = (items + nslice - 1) / nslice;
    const int lo = slice * per;
    const int hi = (lo + per < items) ? lo + per : items;
    for (int t = lo + tid; t < hi; t += 256) {
      const int i0 = t * 8;
      if (i0 + 8 <= jb.n) {
        const float4 a = *(const float4*)(src + i0);
        const float4 b = *(const float4*)(src + i0 + 4);
        u16 o[8] = {f2bf(a.x), f2bf(a.y), f2bf(a.z), f2bf(a.w),
                    f2bf(b.x), f2bf(b.y), f2bf(b.z), f2bf(b.w)};
        int off = i0;
        if (jb.mode == 1) {
          const int col = i0 >> 9, k0 = i0 & 511;
          off = (col >> 5) * 16384 + (k0 >> 5) * 1024 + ((k0 >> 3) & 3) * 256 + (col & 31) * 8;
        }
        *(uint4*)(dst + off) = *(uint4*)o;
      } else {
        for (int k = i0; k < jb.n; ++k) dst[k] = f2bf(src[k]);
      }
    }
  }
}

// ---- per-wave DMA: 2KB chunk; l wave-uniform, src per-lane
__device__ __forceinline__ void stage2k(const char* g, u16* l, int lane) {
  gl_lds16(g + lane * 16, l);
  gl_lds16(g + 1024 + lane * 16, l + 512);
}

// ---- per-wave streamed GEMM: wave owns 32 cols (global cols cb + wid*32 ..).
// Wg/Wn point at this BLOCK's 4-slice region (128 cols = 4 x 32768 B).
// Ledger: entering iter c, chunks c..c+3 in flight. vmcnt(6) -> chunk c done.
// ds_read + MFMA; lgkmcnt(0) -> reads landed; restage slot c&3 w/ chunk c+4
// (or next layer's c-12). Tail (no next): vmcnt 6/4/2/0 at c=12..15.
__device__ __forceinline__ void gemm_pw(const u16* Xlds, const char* Wg, const char* Wn,
                                        u16* wb, const u16* bias, int wid, int lane,
                                        f32x4 acc[2]) {
  const int rc = lane & 15, kb = lane >> 4;
  acc[0] = (f32x4){0.f, 0.f, 0.f, 0.f};
  acc[1] = acc[0];
  const char* gw = Wg + wid * 32768;
  const char* gn = Wn ? Wn + wid * 32768 : nullptr;
#pragma unroll
  for (int c = 0; c < 16; ++c) {
    if (gn || c <= 12) asm volatile("s_waitcnt vmcnt(6)" ::: "memory");
    else if (c == 13) asm volatile("s_waitcnt vmcnt(4)" ::: "memory");
    else if (c == 14) asm volatile("s_waitcnt vmcnt(2)" ::: "memory");
    else asm volatile("s_waitcnt vmcnt(0)" ::: "memory");
    __builtin_amdgcn_sched_barrier(0);
    const u16* B = wb + (c & 3) * 1024;
    const bf16x8 a = *(const bf16x8*)&Xlds[rc * LSTR + c * 32 + kb * 8];
    const bf16x8 b0 = *(const bf16x8*)&B[kb * 256 + rc * 8];
    const bf16x8 b1 = *(const bf16x8*)&B[kb * 256 + (rc + 16) * 8];
    acc[0] = MFMA(a, b0, acc[0]);
    acc[1] = MFMA(a, b1, acc[1]);
    asm volatile("s_waitcnt lgkmcnt(0)" ::: "memory");
    __builtin_amdgcn_sched_barrier(0);
    if (c < 12) stage2k(gw + (c + 4) * 2048, wb + (c & 3) * 1024, lane);
    else if (gn) stage2k(gn + (c - 12) * 2048, wb + (c & 3) * 1024, lane);
  }
#pragma unroll
  for (int nt = 0; nt < 2; ++nt) {
    const float bv = bf2f(bias[wid * 32 + nt * 16 + rc]);
#pragma unroll
    for (int r = 0; r < 4; ++r) acc[nt][r] += bv;
  }
}

// store wave's 16x32 slice into global act
__device__ __forceinline__ void store_act(u16* act, int r0, int cb, int wid, int lane,
                                          const f32x4 acc[2]) {
  const int cr = lane & 15, rb = (lane >> 4) * 4;
#pragma unroll
  for (int nt = 0; nt < 2; ++nt) {
    const int col = cb + wid * 32 + nt * 16 + cr;
#pragma unroll
    for (int r = 0; r < 4; ++r) act[(size_t)(r0 + rb + r) * 512 + col] = f2bf(acc[nt][r]);
  }
}

// store wave's slice into LDS A at global-col positions
__device__ __forceinline__ void store_A(u16* A, int cb, int wid, int lane, const f32x4 acc[2]) {
  const int cr = lane & 15, rb = (lane >> 4) * 4;
#pragma unroll
  for (int nt = 0; nt < 2; ++nt) {
    const int col = cb + wid * 32 + nt * 16 + cr;
#pragma unroll
    for (int r = 0; r < 4; ++r) A[(rb + r) * LSTR + col] = f2bf(acc[nt][r]);
  }
}

__device__ __forceinline__ void add_A(const u16* A, int cb, int wid, int lane, f32x4 acc[2]) {
  const int cr = lane & 15, rb = (lane >> 4) * 4;
#pragma unroll
  for (int nt = 0; nt < 2; ++nt) {
    const int col = cb + wid * 32 + nt * 16 + cr;
#pragma unroll
    for (int r = 0; r < 4; ++r) acc[nt][r] += bf2f(A[(rb + r) * LSTR + col]);
  }
}

__device__ __forceinline__ void add_glb_f32(const float* g, int cb, int wid, int lane,
                                            f32x4 acc[2]) {
  const int cr = lane & 15, rb = (lane >> 4) * 4;
#pragma unroll
  for (int nt = 0; nt < 2; ++nt) {
    const int col = cb + wid * 32 + nt * 16 + cr;
#pragma unroll
    for (int r = 0; r < 4; ++r) acc[nt][r] += g[(size_t)(rb + r) * 512 + col];
  }
}

// load full 16x512 bf16 rows from act into A
__device__ __forceinline__ void load_act(const u16* act, u16* A, int r0, int tid) {
  for (int i = tid; i < 1024; i += 256) {
    const int r = i >> 6, c8 = (i & 63) * 8;
    *(uint4*)&A[r * LSTR + c8] = *(const uint4*)&act[(size_t)(r0 + r) * 512 + c8];
  }
}

// LayerNorm in place on A: wave wid handles rows wid*4..wid*4+3
__device__ __forceinline__ void ln4(u16* A, const u16* g, const u16* b, int wid, int lane) {
#pragma unroll
  for (int rr = 0; rr < 4; ++rr) {
    const int row = wid * 4 + rr;
    float s = 0.f, q = 0.f;
#pragma unroll
    for (int c = lane; c < 512; c += 64) {
      const float v = bf2f(A[row * LSTR + c]);
      s += v; q += v * v;
    }
#pragma unroll
    for (int m = 1; m < 64; m <<= 1) {
      s += __shfl_xor(s, m, 64);
      q += __shfl_xor(q, m, 64);
    }
    const float mu = s * (1.f / 512.f);
    const float rs = rsqrtf(q * (1.f / 512.f) - mu * mu + 1e-5f);
#pragma unroll
    for (int c = lane; c < 512; c += 64) {
      const float v = (bf2f(A[row * LSTR + c]) - mu) * rs * bf2f(g[c]) + bf2f(b[c]);
      A[row * LSTR + c] = f2bf(v);
    }
  }
}

// ---- k_prot: pwr (8 pieces x 4 rot) from RAW f32. 32 blocks = j(4) x colgrp(8).
__global__ __launch_bounds__(256) void k_prot(const float* __restrict__ pemb,
                                              const float* __restrict__ rot_w,
                                              const float* __restrict__ rot_b,
                                              u16* __restrict__ pwr_ws) {
  __shared__ __align__(16) u16 A[16 * LSTR];
  const int tid = threadIdx.x, lane = tid & 63, wid = tid >> 6;
  const int j = blockIdx.x >> 3, g = blockIdx.x & 7;
  for (int idx = tid; idx < 16 * 64; idx += 256) {
    const int r = idx >> 6, c8 = (idx & 63) * 8;
    if (r < 8) {
      const float4 a = *(const float4*)(pemb + r * 512 + c8);
      const float4 b = *(const float4*)(pemb + r * 512 + c8 + 4);
      bf16x8 v = f8_to_bf(a, b);
      *(bf16x8*)&A[r * LSTR + c8] = v;
    } else {
      uint4 z = {0u, 0u, 0u, 0u};
      *(uint4*)&A[r * LSTR + c8] = z;
    }
  }
  __syncthreads();
  const int rc = lane & 15, kb = lane >> 4, rb = (lane >> 4) * 4;
  const int col = g * 64 + wid * 16 + rc;
  const bf16x8* ab = reinterpret_cast<const bf16x8*>(A) + rc * (LSTR / 8) + kb;
  const float* wf = rot_w + (size_t)(j * 512 + col) * 512 + kb * 8;
  f32x4 acc = (f32x4){0.f, 0.f, 0.f, 0.f};
#pragma unroll
  for (int ks = 0; ks < 16; ++ks) {
    const float4 w0 = *(const float4*)(wf + ks * 32);
    const float4 w1 = *(const float4*)(wf + ks * 32 + 4);
    acc = MFMA(ab[ks * 4], f8_to_bf(w0, w1), acc);
  }
  const float bv = rot_b[j * 512 + col];
#pragma unroll
  for (int r = 0; r < 4; ++r) {
    const int p = rb + r;
    if (p < 8) pwr_ws[(size_t)(p * 4 + j) * 512 + col] = f2bf(acc[r] + bv);
  }
}

// ---- k_pkv: kk/vv[32][512] f32 from pwr + RAW f32 k_w/v_w. 32 blocks.
__global__ __launch_bounds__(256) void k_pkv(const u16* __restrict__ pwr_ws,
                                             const float* __restrict__ k_w,
                                             const float* __restrict__ k_b,
                                             const float* __restrict__ v_w,
                                             const float* __restrict__ v_b,
                                             float* __restrict__ kk_ws,
                                             float* __restrict__ vv_ws) {
  __shared__ __align__(16) u16 A[32 * LSTR];
  const int tid = threadIdx.x, lane = tid & 63, wid = tid >> 6;
  const int t = blockIdx.x >> 4, g = blockIdx.x & 15;
  for (int idx = tid; idx < 32 * 64; idx += 256) {
    const int r = idx >> 6, c = idx & 63;
    *(uint4*)&A[r * LSTR + c * 8] = ((const uint4*)pwr_ws)[r * 64 + c];
  }
  __syncthreads();
  const float* W = t ? v_w : k_w;
  const float* Bb = t ? v_b : k_b;
  float* out = t ? vv_ws : kk_ws;
  const int rc = lane & 15, kb = lane >> 4, rb = (lane >> 4) * 4;
  const int rowt = wid >> 1;
  const int col = g * 32 + (wid & 1) * 16 + rc;
  const bf16x8* ab = reinterpret_cast<const bf16x8*>(A) + (rowt * 16 + rc) * (LSTR / 8) + kb;
  const float* wf = W + (size_t)col * 512 + kb * 8;
  f32x4 acc = (f32x4){0.f, 0.f, 0.f, 0.f};
#pragma unroll
  for (int ks = 0; ks < 16; ++ks) {
    const float4 w0 = *(const float4*)(wf + ks * 32);
    const float4 w1 = *(const float4*)(wf + ks * 32 + 4);
    acc = MFMA(ab[ks * 4], f8_to_bf(w0, w1), acc);
  }
  const float bv = Bb[col];
#pragma unroll
  for (int r = 0; r < 4; ++r)
    out[(size_t)(rowt * 16 + rb + r) * 512 + col] = acc[r] + bv;
}

// ---- main: 128 blocks (32 row-tiles x 4 col-tiles) x 256 thr (4 waves).
// Block (br,bc): rows br*16..+15, cols bc*128..+127 (waves own 32 cols each).
// Grid barriers between layers; activations via global act buffer.
__global__ __launch_bounds__(256) void k_main(
    const float* __restrict__ state32, const float* __restrict__ mem32,
    const int* __restrict__ queue, char* __restrict__ ws,
    const float* __restrict__ kk_ws, const float* __restrict__ vv_ws, Jobs jobs,
    float* __restrict__ out_pol, float* __restrict__ out_val) {
  __shared__ __align__(16) u16 A[16 * LSTR];
  __shared__ __align__(16) u16 WB[4 * 4096];  // 4 waves x (4 x 2KB ring)
  __shared__ int piece_s[16];
  __shared__ int qs_s;
  const int tid = threadIdx.x;
  const int lane = tid & 63, wid = tid >> 6;
  const int bc = blockIdx.x & 3, br = blockIdx.x >> 2;
  const int r0 = br * 16, cb = bc * 128;
  u16* wb = &WB[wid * 4096];
  u16* act = (u16*)(ws + WS_ACT);
  int* ctr = (int*)(ws + WS_CTR);
  const int wofs = bc * 131072;  // this block's 4-slice region within a weight

  const u16* a0v_b = (const u16*)(ws + WS_A0VB) + cb;
  const u16* a0o_b = (const u16*)(ws + WS_A0OB) + cb;
  const u16* q_b   = (const u16*)(ws + WS_QB) + cb;
  const u16* qkv_b = (const u16*)(ws + WS_QKVB) + cb;
  const u16* que_b = (const u16*)(ws + WS_QUEB) + cb;
  const u16* a1v_b = (const u16*)(ws + WS_A1VB) + cb;
  const u16* a1o_b = (const u16*)(ws + WS_A1OB) + cb;
  const u16* val_b = (const u16*)(ws + WS_VALB) + cb;
  const u16* pol_w = (const u16*)(ws + WS_POL);
  const u16* pol_b = (const u16*)(ws + WS_POLB);
  const u16* an_g = (const u16*)(ws + WS_ANG);  const u16* an_b = (const u16*)(ws + WS_ANB);
  const u16* fn_g = (const u16*)(ws + WS_FNG);  const u16* fn_b = (const u16*)(ws + WS_FNB);

  // phase 0: weight conversion (sliced over 128 blocks) + state load + queue probe
  conv_part(jobs, ws, blockIdx.x, 128);
  for (int i = tid; i < 1024; i += 256) {  // state f32 -> A bf16 (16x512)
    const int r = i >> 6, c8 = (i & 63) * 8;
    const float* src = state32 + (size_t)(r0 + r) * 512 + c8;
    const float4 a = *(const float4*)src;
    const float4 b = *(const float4*)(src + 4);
    bf16x8 v = f8_to_bf(a, b);
    *(bf16x8*)&A[r * LSTR + c8] = v;
  }
  if (tid == 0) {  // int64-vs-int32 probe
    int odd = 0;
    for (int i = 1; i < 128; i += 2) odd += (queue[i] != 0);
    qs_s = (odd == 0) ? 2 : 1;
  }
  gridbar(ctr, 128 * 1, tid);  // weights converted; A + qs_s visible
  if (tid < 16) piece_s[tid] = queue[(size_t)(r0 + tid) * 5 * qs_s] & 7;

  // start this block's L1 DMA stream (chunks 0..3 per wave)
  {
    const char* g0 = ws + WS_A0V + wofs + wid * 32768;
    stage2k(g0, wb, lane);
    stage2k(g0 + 2048, wb + 1024, lane);
    stage2k(g0 + 4096, wb + 2048, lane);
    stage2k(g0 + 6144, wb + 3072, lane);
  }

  f32x4 acc[2], res[2];
  // L1: v0 = state @ a0v^T
  gemm_pw(A, ws + WS_A0V + wofs, ws + WS_A0O + wofs, wb, a0v_b, wid, lane, acc);
  store_act(act, r0, cb, wid, lane, acc);
  gridbar(ctr, 128 * 2, tid);
  load_act(act, A, r0, tid);
  __syncthreads();
  // L2: s0 = v0 @ a0o^T (residual to regs)
  gemm_pw(A, ws + WS_A0O + wofs, ws + WS_QW + wofs, wb, a0o_b, wid, lane, acc);
  res[0] = acc[0]; res[1] = acc[1];
  store_act(act, r0, cb, wid, lane, acc);
  gridbar(ctr, 128 * 3, tid);
  load_act(act, A, r0, tid);
  __syncthreads();
  // L3: qv = s0 @ q_w^T -> local A (own cols); then attention (col-local)
  gemm_pw(A, ws + WS_QW + wofs, ws + WS_QKV + wofs, wb, q_b, wid, lane, acc);
  __syncthreads();  // all waves done reading A before overwrite
  store_A(A, cb, wid, lane, acc);
  __syncthreads();
  if (tid < 32) {  // (r, hh): head h = bc*2+hh, cols h*64..h*64+63 (inside own slice)
    const int r = tid >> 1, hh = tid & 1;
    const int h = bc * 2 + hh;
    const int p = piece_s[r];
    const u16* qrow = &A[r * LSTR + h * 64];
    const float* kkp = kk_ws + (size_t)(p * 4) * 512 + h * 64;
    const float* vvp = vv_ws + (size_t)(p * 4) * 512 + h * 64;
    float lg[4];
#pragma unroll
    for (int jj = 0; jj < 4; ++jj) {
      float s = 0.f;
      const float* kj = kkp + jj * 512;
#pragma unroll
      for (int d = 0; d < 64; d += 4) {
        const float4 kv = *(const float4*)(kj + d);
        s += bf2f(qrow[d]) * kv.x + bf2f(qrow[d + 1]) * kv.y + bf2f(qrow[d + 2]) * kv.z +
             bf2f(qrow[d + 3]) * kv.w;
      }
      lg[jj] = s * 0.125f;
    }
    const float m = fmaxf(fmaxf(lg[0], lg[1]), fmaxf(lg[2], lg[3]));
    float e0 = __expf(lg[0] - m), e1 = __expf(lg[1] - m);
    float e2 = __expf(lg[2] - m), e3 = __expf(lg[3] - m);
    const float inv = 1.f / (e0 + e1 + e2 + e3);
    e0 *= inv; e1 *= inv; e2 *= inv; e3 *= inv;
    u16* orow = &act[(size_t)(r0 + r) * 512 + h * 64];
#pragma unroll
    for (int d = 0; d < 64; d += 4) {
      const float4 v0 = *(const float4*)(vvp + 0 * 512 + d);
      const float4 v1 = *(const float4*)(vvp + 1 * 512 + d);
      const float4 v2 = *(const float4*)(vvp + 2 * 512 + d);
      const float4 v3 = *(const float4*)(vvp + 3 * 512 + d);
      orow[d + 0] = f2bf(e0 * v0.x + e1 * v1.x + e2 * v2.x + e3 * v3.x);
      orow[d + 1] = f2bf(e0 * v0.y + e1 * v1.y + e2 * v2.y + e3 * v3.y);
      orow[d + 2] = f2bf(e0 * v0.z + e1 * v1.z + e2 * v2.z + e3 * v3.z);
      orow[d + 3] = f2bf(e0 * v0.w + e1 * v1.w + e2 * v2.w + e3 * v3.w);
    }
  }
  gridbar(ctr, 128 * 4, tid);
  load_act(act, A, r0, tid);
  __syncthreads();
  // L4: x1 = s0(res) + attn @ qkv^T
  gemm_pw(A, ws + WS_QKV + wofs, ws + WS_QUE + wofs, wb, qkv_b, wid, lane, acc);
  acc[0] += res[0]; acc[1] += res[1];
  store_act(act, r0, cb, wid, lane, acc);
  gridbar(ctr, 128 * 5, tid);
  load_act(act, A, r0, tid);
  __syncthreads();
  ln4(A, an_g, an_b, wid, lane);  // s1 in A
  __syncthreads();
  // L5: x2 = s1 + s1 @ que_w^T
  gemm_pw(A, ws + WS_QUE + wofs, ws + WS_A1V + wofs, wb, que_b, wid, lane, acc);
  add_A(A, cb, wid, lane, acc);
  store_act(act, r0, cb, wid, lane, acc);
  gridbar(ctr, 128 * 6, tid);
  load_act(act, A, r0, tid);
  __syncthreads();
  ln4(A, fn_g, fn_b, wid, lane);  // s2 in A
  __syncthreads();
  // L6: v1 = s2 @ a1v^T
  gemm_pw(A, ws + WS_A1V + wofs, ws + WS_A1O + wofs, wb, a1v_b, wid, lane, acc);
  store_act(act, r0, cb, wid, lane, acc);
  gridbar(ctr, 128 * 7, tid);
  load_act(act, A, r0, tid);
  __syncthreads();
  // L7: xo = v1 @ a1o^T + memory
  gemm_pw(A, ws + WS_A1O + wofs, ws + WS_VAL + wofs, wb, a1o_b, wid, lane, acc);
  add_glb_f32(mem32 + (size_t)r0 * 512, cb, wid, lane, acc);
  store_act(act, r0, cb, wid, lane, acc);
  gridbar(ctr, 128 * 8, tid);
  load_act(act, A, r0, tid);  // xo full rows
  __syncthreads();
  // L8: val = xo @ val_w^T -> out (f32)
  gemm_pw(A, ws + WS_VAL + wofs, nullptr, wb, val_b, wid, lane, acc);
  {
    const int cr = lane & 15, rb = (lane >> 4) * 4;
#pragma unroll
    for (int nt = 0; nt < 2; ++nt) {
      const int col = cb + wid * 32 + nt * 16 + cr;
#pragma unroll
      for (int r = 0; r < 4; ++r) out_val[(size_t)(r0 + rb + r) * 512 + col] = acc[nt][r];
    }
  }
  // L9: pol (10 cols) - bc==0 blocks, wave 0
  if (bc == 0 && wid == 0) {
    const int rc = lane & 15, kb = lane >> 4;
    const int wrow = rc < 10 ? rc : 0;
    const bf16x8* ab = reinterpret_cast<const bf16x8*>(A) + rc * (LSTR / 8) + kb;
    const bf16x8* wbp = reinterpret_cast<const bf16x8*>(pol_w) + wrow * 64 + kb;
    f32x4 pa = (f32x4){0.f, 0.f, 0.f, 0.f};
#pragma unroll
    for (int ks = 0; ks < 16; ++ks) pa = MFMA(ab[ks * 4], wbp[ks * 4], pa);
    if (rc < 10) {
      const float bv = bf2f(pol_b[rc]);
      const int rb = (lane >> 4) * 4;
#pragma unroll
      for (int r = 0; r < 4; ++r) out_pol[(size_t)(r0 + rb + r) * 10 + rc] = pa[r] + bv;
    }
  }
}

extern "C" void kernel_launch(void* const* d_in, const int* in_sizes, int n_in, void* d_out,
                              int out_size, void* d_ws, size_t ws_size, hipStream_t stream) {
  (void)in_sizes; (void)n_in; (void)out_size; (void)ws_size;
  char* ws = (char*)d_ws;

  Jobs jobs;
  int ji = 0;
  auto add = [&](int idx, int eoff, int n, int off, int mode) {
    jobs.j[ji].base = d_in[idx]; jobs.j[ji].eoff = eoff; jobs.j[ji].n = n;
    jobs.j[ji].dstoff = off; jobs.j[ji].mode = mode; ++ji;
  };
  add(38, 524288, 262144, WS_A0V, 1);   // a0_in_w rows [1024:1536] (v-slice)
  add(40, 0, 262144, WS_A0O, 1);
  add(12, 0, 262144, WS_QW, 1);
  add(18, 0, 262144, WS_QKV, 1);
  add(20, 0, 262144, WS_QUE, 1);
  add(42, 524288, 262144, WS_A1V, 1);   // a1_in_w rows [1024:1536]
  add(44, 0, 262144, WS_A1O, 1);
  add(48, 0, 262144, WS_VAL, 1);
  add(46, 0, 5120, WS_POL, 0);
  add(39, 1024, 512, WS_A0VB, 0);
  add(41, 0, 512, WS_A0OB, 0);
  add(13, 0, 512, WS_QB, 0);
  add(19, 0, 512, WS_QKVB, 0);
  add(21, 0, 512, WS_QUEB, 0);
  add(43, 1024, 512, WS_A1VB, 0);
  add(45, 0, 512, WS_A1OB, 0);
  add(49, 0, 512, WS_VALB, 0);
  add(22, 0, 512, WS_ANG, 0);
  add(23, 0, 512, WS_ANB, 0);
  add(24, 0, 512, WS_FNG, 0);
  add(25, 0, 512, WS_FNB, 0);
  add(47, 0, 10, WS_POLB, 0);

  hipMemsetAsync(ws + WS_CTR, 0, 4, stream);  // reset grid-barrier counter每 launch
  k_prot<<<dim3(32), dim3(256), 0, stream>>>((const float*)d_in[9], (const float*)d_in[10],
                                             (const float*)d_in[11], (u16*)(ws + WS_PWR));
  k_pkv<<<dim3(32), dim3(256), 0, stream>>>((const u16*)(ws + WS_PWR), (const float*)d_in[14],
                                            (const float*)d_in[15], (const float*)d_in[16],
                                            (const float*)d_in[17], (float*)(ws + WS_KK),
                                            (float*)(ws + WS_VV));

  float* out_pol = (float*)d_out;
  float* out_val = out_pol + 512 * 10;
  k_main<<<dim3(128), dim3(256), 0, stream>>>(
      (const float*)d_in[3], (const float*)d_in[4], (const int*)d_in[1], ws,
      (const float*)(ws + WS_KK), (const float*)(ws + WS_VV), jobs, out_pol, out_val);
}

// Round 9
// 114.695 us; speedup vs baseline: 1.0879x; 1.0879x over previous
//
#include <hip/hip_runtime.h>

typedef unsigned short u16;
typedef __attribute__((ext_vector_type(8))) short bf16x8;
typedef __attribute__((ext_vector_type(4))) float f32x4;

#define LSTR 520  // bf16 elems per LDS row: 512 + 8 pad

// ---------------- workspace layout (bytes) ----------------
#define WS_ACT     0          // 512x512 bf16 activations (524288 B)
#define WS_A0V     524288
#define WS_A0O     1048576
#define WS_QW      1572864
#define WS_QKV     2097152
#define WS_QUE     2621440
#define WS_A1V     3145728
#define WS_A1O     3670016
#define WS_VAL     4194304
#define WS_POL     4718592
#define WS_PWR     7882752
#define WS_KK      7915520
#define WS_VV      7981056
#define WS_A0VB    8574976
#define WS_A0OB    (WS_A0VB + 1024)
#define WS_QB      (WS_A0VB + 2048)
#define WS_QKVB    (WS_A0VB + 5120)
#define WS_QUEB    (WS_A0VB + 6144)
#define WS_A1VB    (WS_A0VB + 7168)
#define WS_A1OB    (WS_A0VB + 8192)
#define WS_VALB    (WS_A0VB + 9216)
#define WS_ANG     (WS_A0VB + 10240)
#define WS_ANB     (WS_A0VB + 11264)
#define WS_FNG     (WS_A0VB + 12288)
#define WS_FNB     (WS_A0VB + 13312)
#define WS_POLB    (WS_A0VB + 14336)
#define WS_CTR     8650752    // grid-barrier counter (4 B), memset to 0 each launch

__device__ __forceinline__ float bf2f(u16 u) {
  union { unsigned int i; float f; } v; v.i = ((unsigned int)u) << 16; return v.f;
}
__device__ __forceinline__ u16 f2bf(float f) {
  union { float f; unsigned int i; } v; v.f = f;
  unsigned int r = v.i + 0x7fffu + ((v.i >> 16) & 1u);
  return (u16)(r >> 16);
}
__device__ __forceinline__ bf16x8 f8_to_bf(const float4 a, const float4 b) {
  u16 o[8] = {f2bf(a.x), f2bf(a.y), f2bf(a.z), f2bf(a.w),
              f2bf(b.x), f2bf(b.y), f2bf(b.z), f2bf(b.w)};
  return *(bf16x8*)o;
}
__device__ __forceinline__ f32x4 MFMA(bf16x8 a, bf16x8 b, f32x4 c) {
  return __builtin_amdgcn_mfma_f32_16x16x32_bf16(a, b, c, 0, 0, 0);
}
__device__ __forceinline__ void gl_lds16(const void* g, void* l) {
  __builtin_amdgcn_global_load_lds((const __attribute__((address_space(1))) void*)g,
                                   (__attribute__((address_space(3))) void*)l, 16, 0, 0);
}

// ---- device-wide barrier (128 blocks co-resident; monotonic phase targets).
// Arrival: per-wave vmcnt(0) (stores in L2) -> tid0 __threadfence (L2 writeback)
// + ONE atomicAdd. Poll: relaxed agent-scope LOAD (no RMW contention) with
// s_sleep backoff. Acquire: __threadfence (invalidate) + __syncthreads.
__device__ __forceinline__ void gridbar(int* ctr, int target, int tid) {
  asm volatile("s_waitcnt vmcnt(0)" ::: "memory");
  __syncthreads();
  if (tid == 0) {
    __threadfence();
    atomicAdd(ctr, 1);
    int it = 0;
    while (__hip_atomic_load(ctr, __ATOMIC_RELAXED, __HIP_MEMORY_SCOPE_AGENT) < target) {
      __builtin_amdgcn_s_sleep(4);
      if (++it > 5000000) break;  // bounded: fail loud, not hang
    }
    __threadfence();
  }
  __syncthreads();
}

// ---------------- weight conversion kernel ----------------
// mode 0: plain f32->bf16. mode 1: per-32col-slice chunked for 512x512 W:
// elem (col,k): dst = (col>>5)*16384 + (k>>5)*1024 + ((k>>3)&3)*256 + (col&31)*8 + (k&7)
#define NJOBS 22
struct Job { const void* base; int eoff; int n; int dstoff; int mode; };
struct Jobs { Job j[NJOBS]; };

__global__ __launch_bounds__(256) void k_convert(Jobs jobs, char* __restrict__ ws) {
  const Job jb = jobs.j[blockIdx.y];
  const int i0 = (blockIdx.x * 256 + threadIdx.x) * 8;
  if (i0 >= jb.n) return;
  u16* dst = (u16*)(ws + jb.dstoff);
  const float* src = (const float*)jb.base + jb.eoff;
  if (i0 + 8 <= jb.n) {
    const float4 a = *(const float4*)(src + i0);
    const float4 b = *(const float4*)(src + i0 + 4);
    u16 o[8] = {f2bf(a.x), f2bf(a.y), f2bf(a.z), f2bf(a.w),
                f2bf(b.x), f2bf(b.y), f2bf(b.z), f2bf(b.w)};
    int off = i0;
    if (jb.mode == 1) {
      const int col = i0 >> 9, k0 = i0 & 511;
      off = (col >> 5) * 16384 + (k0 >> 5) * 1024 + ((k0 >> 3) & 3) * 256 + (col & 31) * 8;
    }
    *(uint4*)(dst + off) = *(uint4*)o;
  } else {
    for (int k = i0; k < jb.n; ++k) dst[k] = f2bf(src[k]);
  }
}

// ---- per-wave DMA: 2KB chunk; l wave-uniform, src per-lane
__device__ __forceinline__ void stage2k(const char* g, u16* l, int lane) {
  gl_lds16(g + lane * 16, l);
  gl_lds16(g + 1024 + lane * 16, l + 512);
}

// ---- per-wave streamed GEMM: wave owns 32 cols (global cols cb + wid*32 ..).
// Wg/Wn point at this BLOCK's 4-slice region (128 cols = 4 x 32768 B).
// Ledger: entering iter c, chunks c..c+3 in flight. vmcnt(6) -> chunk c done.
// ds_read + MFMA; lgkmcnt(0) -> reads landed; restage slot c&3 w/ chunk c+4
// (or next layer's c-12). Tail (no next): vmcnt 6/4/2/0 at c=12..15.
__device__ __forceinline__ void gemm_pw(const u16* Xlds, const char* Wg, const char* Wn,
                                        u16* wb, const u16* bias, int wid, int lane,
                                        f32x4 acc[2]) {
  const int rc = lane & 15, kb = lane >> 4;
  acc[0] = (f32x4){0.f, 0.f, 0.f, 0.f};
  acc[1] = acc[0];
  const char* gw = Wg + wid * 32768;
  const char* gn = Wn ? Wn + wid * 32768 : nullptr;
#pragma unroll
  for (int c = 0; c < 16; ++c) {
    if (gn || c <= 12) asm volatile("s_waitcnt vmcnt(6)" ::: "memory");
    else if (c == 13) asm volatile("s_waitcnt vmcnt(4)" ::: "memory");
    else if (c == 14) asm volatile("s_waitcnt vmcnt(2)" ::: "memory");
    else asm volatile("s_waitcnt vmcnt(0)" ::: "memory");
    __builtin_amdgcn_sched_barrier(0);
    const u16* B = wb + (c & 3) * 1024;
    const bf16x8 a = *(const bf16x8*)&Xlds[rc * LSTR + c * 32 + kb * 8];
    const bf16x8 b0 = *(const bf16x8*)&B[kb * 256 + rc * 8];
    const bf16x8 b1 = *(const bf16x8*)&B[kb * 256 + (rc + 16) * 8];
    acc[0] = MFMA(a, b0, acc[0]);
    acc[1] = MFMA(a, b1, acc[1]);
    asm volatile("s_waitcnt lgkmcnt(0)" ::: "memory");
    __builtin_amdgcn_sched_barrier(0);
    if (c < 12) stage2k(gw + (c + 4) * 2048, wb + (c & 3) * 1024, lane);
    else if (gn) stage2k(gn + (c - 12) * 2048, wb + (c & 3) * 1024, lane);
  }
#pragma unroll
  for (int nt = 0; nt < 2; ++nt) {
    const float bv = bf2f(bias[wid * 32 + nt * 16 + rc]);
#pragma unroll
    for (int r = 0; r < 4; ++r) acc[nt][r] += bv;
  }
}

// store wave's 16x32 slice into global act
__device__ __forceinline__ void store_act(u16* act, int r0, int cb, int wid, int lane,
                                          const f32x4 acc[2]) {
  const int cr = lane & 15, rb = (lane >> 4) * 4;
#pragma unroll
  for (int nt = 0; nt < 2; ++nt) {
    const int col = cb + wid * 32 + nt * 16 + cr;
#pragma unroll
    for (int r = 0; r < 4; ++r) act[(size_t)(r0 + rb + r) * 512 + col] = f2bf(acc[nt][r]);
  }
}

// store wave's slice into LDS A at global-col positions
__device__ __forceinline__ void store_A(u16* A, int cb, int wid, int lane, const f32x4 acc[2]) {
  const int cr = lane & 15, rb = (lane >> 4) * 4;
#pragma unroll
  for (int nt = 0; nt < 2; ++nt) {
    const int col = cb + wid * 32 + nt * 16 + cr;
#pragma unroll
    for (int r = 0; r < 4; ++r) A[(rb + r) * LSTR + col] = f2bf(acc[nt][r]);
  }
}

__device__ __forceinline__ void add_A(const u16* A, int cb, int wid, int lane, f32x4 acc[2]) {
  const int cr = lane & 15, rb = (lane >> 4) * 4;
#pragma unroll
  for (int nt = 0; nt < 2; ++nt) {
    const int col = cb + wid * 32 + nt * 16 + cr;
#pragma unroll
    for (int r = 0; r < 4; ++r) acc[nt][r] += bf2f(A[(rb + r) * LSTR + col]);
  }
}

__device__ __forceinline__ void add_glb_f32(const float* g, int cb, int wid, int lane,
                                            f32x4 acc[2]) {
  const int cr = lane & 15, rb = (lane >> 4) * 4;
#pragma unroll
  for (int nt = 0; nt < 2; ++nt) {
    const int col = cb + wid * 32 + nt * 16 + cr;
#pragma unroll
    for (int r = 0; r < 4; ++r) acc[nt][r] += g[(size_t)(rb + r) * 512 + col];
  }
}

// load full 16x512 bf16 rows from act into A
__device__ __forceinline__ void load_act(const u16* act, u16* A, int r0, int tid) {
  for (int i = tid; i < 1024; i += 256) {
    const int r = i >> 6, c8 = (i & 63) * 8;
    *(uint4*)&A[r * LSTR + c8] = *(const uint4*)&act[(size_t)(r0 + r) * 512 + c8];
  }
}

// LayerNorm in place on A: wave wid handles rows wid*4..wid*4+3
__device__ __forceinline__ void ln4(u16* A, const u16* g, const u16* b, int wid, int lane) {
#pragma unroll
  for (int rr = 0; rr < 4; ++rr) {
    const int row = wid * 4 + rr;
    float s = 0.f, q = 0.f;
#pragma unroll
    for (int c = lane; c < 512; c += 64) {
      const float v = bf2f(A[row * LSTR + c]);
      s += v; q += v * v;
    }
#pragma unroll
    for (int m = 1; m < 64; m <<= 1) {
      s += __shfl_xor(s, m, 64);
      q += __shfl_xor(q, m, 64);
    }
    const float mu = s * (1.f / 512.f);
    const float rs = rsqrtf(q * (1.f / 512.f) - mu * mu + 1e-5f);
#pragma unroll
    for (int c = lane; c < 512; c += 64) {
      const float v = (bf2f(A[row * LSTR + c]) - mu) * rs * bf2f(g[c]) + bf2f(b[c]);
      A[row * LSTR + c] = f2bf(v);
    }
  }
}

// ---- k_prot: pwr (8 pieces x 4 rot) from RAW f32. 32 blocks = j(4) x colgrp(8).
__global__ __launch_bounds__(256) void k_prot(const float* __restrict__ pemb,
                                              const float* __restrict__ rot_w,
                                              const float* __restrict__ rot_b,
                                              u16* __restrict__ pwr_ws) {
  __shared__ __align__(16) u16 A[16 * LSTR];
  const int tid = threadIdx.x, lane = tid & 63, wid = tid >> 6;
  const int j = blockIdx.x >> 3, g = blockIdx.x & 7;
  for (int idx = tid; idx < 16 * 64; idx += 256) {
    const int r = idx >> 6, c8 = (idx & 63) * 8;
    if (r < 8) {
      const float4 a = *(const float4*)(pemb + r * 512 + c8);
      const float4 b = *(const float4*)(pemb + r * 512 + c8 + 4);
      bf16x8 v = f8_to_bf(a, b);
      *(bf16x8*)&A[r * LSTR + c8] = v;
    } else {
      uint4 z = {0u, 0u, 0u, 0u};
      *(uint4*)&A[r * LSTR + c8] = z;
    }
  }
  __syncthreads();
  const int rc = lane & 15, kb = lane >> 4, rb = (lane >> 4) * 4;
  const int col = g * 64 + wid * 16 + rc;
  const bf16x8* ab = reinterpret_cast<const bf16x8*>(A) + rc * (LSTR / 8) + kb;
  const float* wf = rot_w + (size_t)(j * 512 + col) * 512 + kb * 8;
  f32x4 acc = (f32x4){0.f, 0.f, 0.f, 0.f};
#pragma unroll
  for (int ks = 0; ks < 16; ++ks) {
    const float4 w0 = *(const float4*)(wf + ks * 32);
    const float4 w1 = *(const float4*)(wf + ks * 32 + 4);
    acc = MFMA(ab[ks * 4], f8_to_bf(w0, w1), acc);
  }
  const float bv = rot_b[j * 512 + col];
#pragma unroll
  for (int r = 0; r < 4; ++r) {
    const int p = rb + r;
    if (p < 8) pwr_ws[(size_t)(p * 4 + j) * 512 + col] = f2bf(acc[r] + bv);
  }
}

// ---- k_pkv: kk/vv[32][512] f32 from pwr + RAW f32 k_w/v_w. 32 blocks.
__global__ __launch_bounds__(256) void k_pkv(const u16* __restrict__ pwr_ws,
                                             const float* __restrict__ k_w,
                                             const float* __restrict__ k_b,
                                             const float* __restrict__ v_w,
                                             const float* __restrict__ v_b,
                                             float* __restrict__ kk_ws,
                                             float* __restrict__ vv_ws) {
  __shared__ __align__(16) u16 A[32 * LSTR];
  const int tid = threadIdx.x, lane = tid & 63, wid = tid >> 6;
  const int t = blockIdx.x >> 4, g = blockIdx.x & 15;
  for (int idx = tid; idx < 32 * 64; idx += 256) {
    const int r = idx >> 6, c = idx & 63;
    *(uint4*)&A[r * LSTR + c * 8] = ((const uint4*)pwr_ws)[r * 64 + c];
  }
  __syncthreads();
  const float* W = t ? v_w : k_w;
  const float* Bb = t ? v_b : k_b;
  float* out = t ? vv_ws : kk_ws;
  const int rc = lane & 15, kb = lane >> 4, rb = (lane >> 4) * 4;
  const int rowt = wid >> 1;
  const int col = g * 32 + (wid & 1) * 16 + rc;
  const bf16x8* ab = reinterpret_cast<const bf16x8*>(A) + (rowt * 16 + rc) * (LSTR / 8) + kb;
  const float* wf = W + (size_t)col * 512 + kb * 8;
  f32x4 acc = (f32x4){0.f, 0.f, 0.f, 0.f};
#pragma unroll
  for (int ks = 0; ks < 16; ++ks) {
    const float4 w0 = *(const float4*)(wf + ks * 32);
    const float4 w1 = *(const float4*)(wf + ks * 32 + 4);
    acc = MFMA(ab[ks * 4], f8_to_bf(w0, w1), acc);
  }
  const float bv = Bb[col];
#pragma unroll
  for (int r = 0; r < 4; ++r)
    out[(size_t)(rowt * 16 + rb + r) * 512 + col] = acc[r] + bv;
}

// ---- main: 128 blocks (32 row-tiles x 4 col-tiles) x 256 thr (4 waves).
// Block (br,bc): rows br*16..+15, cols bc*128..+127 (waves own 32 cols each).
// Grid barriers between layers; activations via global act buffer.
__global__ __launch_bounds__(256) void k_main(
    const float* __restrict__ state32, const float* __restrict__ mem32,
    const int* __restrict__ queue, char* __restrict__ ws,
    const float* __restrict__ kk_ws, const float* __restrict__ vv_ws,
    float* __restrict__ out_pol, float* __restrict__ out_val) {
  __shared__ __align__(16) u16 A[16 * LSTR];
  __shared__ __align__(16) u16 WB[4 * 4096];  // 4 waves x (4 x 2KB ring)
  __shared__ int piece_s[16];
  __shared__ int qs_s;
  const int tid = threadIdx.x;
  const int lane = tid & 63, wid = tid >> 6;
  const int bc = blockIdx.x & 3, br = blockIdx.x >> 2;
  const int r0 = br * 16, cb = bc * 128;
  u16* wb = &WB[wid * 4096];
  u16* act = (u16*)(ws + WS_ACT);
  int* ctr = (int*)(ws + WS_CTR);
  const int wofs = bc * 131072;  // this block's 4-slice region within a weight

  const u16* a0v_b = (const u16*)(ws + WS_A0VB) + cb;
  const u16* a0o_b = (const u16*)(ws + WS_A0OB) + cb;
  const u16* q_b   = (const u16*)(ws + WS_QB) + cb;
  const u16* qkv_b = (const u16*)(ws + WS_QKVB) + cb;
  const u16* que_b = (const u16*)(ws + WS_QUEB) + cb;
  const u16* a1v_b = (const u16*)(ws + WS_A1VB) + cb;
  const u16* a1o_b = (const u16*)(ws + WS_A1OB) + cb;
  const u16* val_b = (const u16*)(ws + WS_VALB) + cb;
  const u16* pol_w = (const u16*)(ws + WS_POL);
  const u16* pol_b = (const u16*)(ws + WS_POLB);
  const u16* an_g = (const u16*)(ws + WS_ANG);  const u16* an_b = (const u16*)(ws + WS_ANB);
  const u16* fn_g = (const u16*)(ws + WS_FNG);  const u16* fn_b = (const u16*)(ws + WS_FNB);

  // weights already converted by k_convert -> start L1 DMA stream immediately
  {
    const char* g0 = ws + WS_A0V + wofs + wid * 32768;
    stage2k(g0, wb, lane);
    stage2k(g0 + 2048, wb + 1024, lane);
    stage2k(g0 + 4096, wb + 2048, lane);
    stage2k(g0 + 6144, wb + 3072, lane);
  }
  // state f32 -> A bf16 (16x512)
  for (int i = tid; i < 1024; i += 256) {
    const int r = i >> 6, c8 = (i & 63) * 8;
    const float* src = state32 + (size_t)(r0 + r) * 512 + c8;
    const float4 a = *(const float4*)src;
    const float4 b = *(const float4*)(src + 4);
    bf16x8 v = f8_to_bf(a, b);
    *(bf16x8*)&A[r * LSTR + c8] = v;
  }
  if (tid == 0) {  // int64-vs-int32 probe
    int odd = 0;
    for (int i = 1; i < 128; i += 2) odd += (queue[i] != 0);
    qs_s = (odd == 0) ? 2 : 1;
  }
  __syncthreads();  // A + qs_s visible (also drains prologue DMA into LDS - fine)
  if (tid < 16) piece_s[tid] = queue[(size_t)(r0 + tid) * 5 * qs_s] & 7;
  // piece_s consumed after L1..L3 syncs below -> ordering safe.

  f32x4 acc[2], res[2];
  // L1: v0 = state @ a0v^T
  gemm_pw(A, ws + WS_A0V + wofs, ws + WS_A0O + wofs, wb, a0v_b, wid, lane, acc);
  store_act(act, r0, cb, wid, lane, acc);
  gridbar(ctr, 128 * 1, tid);
  load_act(act, A, r0, tid);
  __syncthreads();
  // L2: s0 = v0 @ a0o^T (residual to regs)
  gemm_pw(A, ws + WS_A0O + wofs, ws + WS_QW + wofs, wb, a0o_b, wid, lane, acc);
  res[0] = acc[0]; res[1] = acc[1];
  store_act(act, r0, cb, wid, lane, acc);
  gridbar(ctr, 128 * 2, tid);
  load_act(act, A, r0, tid);
  __syncthreads();
  // L3: qv = s0 @ q_w^T -> local A (own cols); then attention (col-local)
  gemm_pw(A, ws + WS_QW + wofs, ws + WS_QKV + wofs, wb, q_b, wid, lane, acc);
  __syncthreads();  // all waves done reading A before overwrite
  store_A(A, cb, wid, lane, acc);
  __syncthreads();
  if (tid < 32) {  // (r, hh): head h = bc*2+hh, cols h*64..h*64+63 (inside own slice)
    const int r = tid >> 1, hh = tid & 1;
    const int h = bc * 2 + hh;
    const int p = piece_s[r];
    const u16* qrow = &A[r * LSTR + h * 64];
    const float* kkp = kk_ws + (size_t)(p * 4) * 512 + h * 64;
    const float* vvp = vv_ws + (size_t)(p * 4) * 512 + h * 64;
    float lg[4];
#pragma unroll
    for (int jj = 0; jj < 4; ++jj) {
      float s = 0.f;
      const float* kj = kkp + jj * 512;
#pragma unroll
      for (int d = 0; d < 64; d += 4) {
        const float4 kv = *(const float4*)(kj + d);
        s += bf2f(qrow[d]) * kv.x + bf2f(qrow[d + 1]) * kv.y + bf2f(qrow[d + 2]) * kv.z +
             bf2f(qrow[d + 3]) * kv.w;
      }
      lg[jj] = s * 0.125f;
    }
    const float m = fmaxf(fmaxf(lg[0], lg[1]), fmaxf(lg[2], lg[3]));
    float e0 = __expf(lg[0] - m), e1 = __expf(lg[1] - m);
    float e2 = __expf(lg[2] - m), e3 = __expf(lg[3] - m);
    const float inv = 1.f / (e0 + e1 + e2 + e3);
    e0 *= inv; e1 *= inv; e2 *= inv; e3 *= inv;
    u16* orow = &act[(size_t)(r0 + r) * 512 + h * 64];
#pragma unroll
    for (int d = 0; d < 64; d += 4) {
      const float4 v0 = *(const float4*)(vvp + 0 * 512 + d);
      const float4 v1 = *(const float4*)(vvp + 1 * 512 + d);
      const float4 v2 = *(const float4*)(vvp + 2 * 512 + d);
      const float4 v3 = *(const float4*)(vvp + 3 * 512 + d);
      orow[d + 0] = f2bf(e0 * v0.x + e1 * v1.x + e2 * v2.x + e3 * v3.x);
      orow[d + 1] = f2bf(e0 * v0.y + e1 * v1.y + e2 * v2.y + e3 * v3.y);
      orow[d + 2] = f2bf(e0 * v0.z + e1 * v1.z + e2 * v2.z + e3 * v3.z);
      orow[d + 3] = f2bf(e0 * v0.w + e1 * v1.w + e2 * v2.w + e3 * v3.w);
    }
  }
  gridbar(ctr, 128 * 3, tid);
  load_act(act, A, r0, tid);
  __syncthreads();
  // L4: x1 = s0(res) + attn @ qkv^T
  gemm_pw(A, ws + WS_QKV + wofs, ws + WS_QUE + wofs, wb, qkv_b, wid, lane, acc);
  acc[0] += res[0]; acc[1] += res[1];
  store_act(act, r0, cb, wid, lane, acc);
  gridbar(ctr, 128 * 4, tid);
  load_act(act, A, r0, tid);
  __syncthreads();
  ln4(A, an_g, an_b, wid, lane);  // s1 in A
  __syncthreads();
  // L5: x2 = s1 + s1 @ que_w^T
  gemm_pw(A, ws + WS_QUE + wofs, ws + WS_A1V + wofs, wb, que_b, wid, lane, acc);
  add_A(A, cb, wid, lane, acc);
  store_act(act, r0, cb, wid, lane, acc);
  gridbar(ctr, 128 * 5, tid);
  load_act(act, A, r0, tid);
  __syncthreads();
  ln4(A, fn_g, fn_b, wid, lane);  // s2 in A
  __syncthreads();
  // L6: v1 = s2 @ a1v^T
  gemm_pw(A, ws + WS_A1V + wofs, ws + WS_A1O + wofs, wb, a1v_b, wid, lane, acc);
  store_act(act, r0, cb, wid, lane, acc);
  gridbar(ctr, 128 * 6, tid);
  load_act(act, A, r0, tid);
  __syncthreads();
  // L7: xo = v1 @ a1o^T + memory
  gemm_pw(A, ws + WS_A1O + wofs, ws + WS_VAL + wofs, wb, a1o_b, wid, lane, acc);
  add_glb_f32(mem32 + (size_t)r0 * 512, cb, wid, lane, acc);
  store_act(act, r0, cb, wid, lane, acc);
  gridbar(ctr, 128 * 7, tid);
  load_act(act, A, r0, tid);  // xo full rows
  __syncthreads();
  // L8: val = xo @ val_w^T -> out (f32)
  gemm_pw(A, ws + WS_VAL + wofs, nullptr, wb, val_b, wid, lane, acc);
  {
    const int cr = lane & 15, rb = (lane >> 4) * 4;
#pragma unroll
    for (int nt = 0; nt < 2; ++nt) {
      const int col = cb + wid * 32 + nt * 16 + cr;
#pragma unroll
      for (int r = 0; r < 4; ++r) out_val[(size_t)(r0 + rb + r) * 512 + col] = acc[nt][r];
    }
  }
  // L9: pol (10 cols) - bc==0 blocks, wave 0
  if (bc == 0 && wid == 0) {
    const int rc = lane & 15, kb = lane >> 4;
    const int wrow = rc < 10 ? rc : 0;
    const bf16x8* ab = reinterpret_cast<const bf16x8*>(A) + rc * (LSTR / 8) + kb;
    const bf16x8* wbp = reinterpret_cast<const bf16x8*>(pol_w) + wrow * 64 + kb;
    f32x4 pa = (f32x4){0.f, 0.f, 0.f, 0.f};
#pragma unroll
    for (int ks = 0; ks < 16; ++ks) pa = MFMA(ab[ks * 4], wbp[ks * 4], pa);
    if (rc < 10) {
      const float bv = bf2f(pol_b[rc]);
      const int rb = (lane >> 4) * 4;
#pragma unroll
      for (int r = 0; r < 4; ++r) out_pol[(size_t)(r0 + rb + r) * 10 + rc] = pa[r] + bv;
    }
  }
}

extern "C" void kernel_launch(void* const* d_in, const int* in_sizes, int n_in, void* d_out,
                              int out_size, void* d_ws, size_t ws_size, hipStream_t stream) {
  (void)in_sizes; (void)n_in; (void)out_size; (void)ws_size;
  char* ws = (char*)d_ws;

  Jobs jobs;
  int ji = 0;
  auto add = [&](int idx, int eoff, int n, int off, int mode) {
    jobs.j[ji].base = d_in[idx]; jobs.j[ji].eoff = eoff; jobs.j[ji].n = n;
    jobs.j[ji].dstoff = off; jobs.j[ji].mode = mode; ++ji;
  };
  add(38, 524288, 262144, WS_A0V, 1);   // a0_in_w rows [1024:1536] (v-slice)
  add(40, 0, 262144, WS_A0O, 1);
  add(12, 0, 262144, WS_QW, 1);
  add(18, 0, 262144, WS_QKV, 1);
  add(20, 0, 262144, WS_QUE, 1);
  add(42, 524288, 262144, WS_A1V, 1);   // a1_in_w rows [1024:1536]
  add(44, 0, 262144, WS_A1O, 1);
  add(48, 0, 262144, WS_VAL, 1);
  add(46, 0, 5120, WS_POL, 0);
  add(39, 1024, 512, WS_A0VB, 0);
  add(41, 0, 512, WS_A0OB, 0);
  add(13, 0, 512, WS_QB, 0);
  add(19, 0, 512, WS_QKVB, 0);
  add(21, 0, 512, WS_QUEB, 0);
  add(43, 1024, 512, WS_A1VB, 0);
  add(45, 0, 512, WS_A1OB, 0);
  add(49, 0, 512, WS_VALB, 0);
  add(22, 0, 512, WS_ANG, 0);
  add(23, 0, 512, WS_ANB, 0);
  add(24, 0, 512, WS_FNG, 0);
  add(25, 0, 512, WS_FNB, 0);
  add(47, 0, 10, WS_POLB, 0);

  hipMemsetAsync(ws + WS_CTR, 0, 4, stream);  // reset grid-barrier counter per launch
  k_convert<<<dim3(128, NJOBS), dim3(256), 0, stream>>>(jobs, ws);
  k_prot<<<dim3(32), dim3(256), 0, stream>>>((const float*)d_in[9], (const float*)d_in[10],
                                             (const float*)d_in[11], (u16*)(ws + WS_PWR));
  k_pkv<<<dim3(32), dim3(256), 0, stream>>>((const u16*)(ws + WS_PWR), (const float*)d_in[14],
                                            (const float*)d_in[15], (const float*)d_in[16],
                                            (const float*)d_in[17], (float*)(ws + WS_KK),
                                            (float*)(ws + WS_VV));

  float* out_pol = (float*)d_out;
  float* out_val = out_pol + 512 * 10;
  k_main<<<dim3(128), dim3(256), 0, stream>>>(
      (const float*)d_in[3], (const float*)d_in[4], (const int*)d_in[1], ws,
      (const float*)(ws + WS_KK), (const float*)(ws + WS_VV), out_pol, out_val);
}

// Round 10
// 66.851 us; speedup vs baseline: 1.8664x; 1.7157x over previous
//
#include <hip/hip_runtime.h>

typedef unsigned short u16;
typedef __attribute__((ext_vector_type(8))) short bf16x8;
typedef __attribute__((ext_vector_type(4))) float f32x4;
typedef __attribute__((ext_vector_type(4))) unsigned int u32x4;

#define LSTR 520  // bf16 elems per LDS row: 512 + 8 pad

// ---------------- workspace layout (bytes) ----------------
#define WS_ACT     0          // 512x512 bf16 activations (524288 B), sc0sc1-coherent
#define WS_A0V     524288
#define WS_A0O     1048576
#define WS_QW      1572864
#define WS_QKV     2097152
#define WS_QUE     2621440
#define WS_A1V     3145728
#define WS_A1O     3670016
#define WS_VAL     4194304
#define WS_POL     4718592
#define WS_PWR     7882752
#define WS_KK      7915520
#define WS_VV      7981056
#define WS_A0VB    8574976
#define WS_A0OB    (WS_A0VB + 1024)
#define WS_QB      (WS_A0VB + 2048)
#define WS_QKVB    (WS_A0VB + 5120)
#define WS_QUEB    (WS_A0VB + 6144)
#define WS_A1VB    (WS_A0VB + 7168)
#define WS_A1OB    (WS_A0VB + 8192)
#define WS_VALB    (WS_A0VB + 9216)
#define WS_ANG     (WS_A0VB + 10240)
#define WS_ANB     (WS_A0VB + 11264)
#define WS_FNG     (WS_A0VB + 12288)
#define WS_FNB     (WS_A0VB + 13312)
#define WS_POLB    (WS_A0VB + 14336)
#define WS_CTR     8650752    // 32 group counters x 128B, memset 0 each launch

__device__ __forceinline__ float bf2f(u16 u) {
  union { unsigned int i; float f; } v; v.i = ((unsigned int)u) << 16; return v.f;
}
__device__ __forceinline__ u16 f2bf(float f) {
  union { float f; unsigned int i; } v; v.f = f;
  unsigned int r = v.i + 0x7fffu + ((v.i >> 16) & 1u);
  return (u16)(r >> 16);
}
__device__ __forceinline__ bf16x8 f8_to_bf(const float4 a, const float4 b) {
  u16 o[8] = {f2bf(a.x), f2bf(a.y), f2bf(a.z), f2bf(a.w),
              f2bf(b.x), f2bf(b.y), f2bf(b.z), f2bf(b.w)};
  return *(bf16x8*)o;
}
__device__ __forceinline__ f32x4 MFMA(bf16x8 a, bf16x8 b, f32x4 c) {
  return __builtin_amdgcn_mfma_f32_16x16x32_bf16(a, b, c, 0, 0, 0);
}
__device__ __forceinline__ void gl_lds16(const void* g, void* l) {
  __builtin_amdgcn_global_load_lds((const __attribute__((address_space(1))) void*)g,
                                   (__attribute__((address_space(3))) void*)l, 16, 0, 0);
}
// system-coherent 16B store (write-through to Infinity Cache; no L2 flush needed)
__device__ __forceinline__ void st16_cc(void* p, u32x4 v) {
  asm volatile("global_store_dwordx4 %0, %1, off sc0 sc1" :: "v"(p), "v"(v) : "memory");
}

// ---- per-row-group barrier (8 col-blocks). Release: vmcnt(0) retires the sc1
// act stores at the coherence point (IF$); relaxed atomicAdd (same coherence
// point) is issued after -> any observer of the count sees the stores via sc1
// loads. NO __threadfence => no L2 writeback/invalidate, weights stay cached.
__device__ __forceinline__ void gridbar(int* grp, int target, int tid) {
  asm volatile("s_waitcnt vmcnt(0)" ::: "memory");
  __syncthreads();
  if (tid == 0) {
    __hip_atomic_fetch_add(grp, 1, __ATOMIC_RELAXED, __HIP_MEMORY_SCOPE_AGENT);
    int it = 0;
    while (__hip_atomic_load(grp, __ATOMIC_RELAXED, __HIP_MEMORY_SCOPE_AGENT) < target) {
      __builtin_amdgcn_s_sleep(2);
      if (++it > 2000000) break;  // bounded: fail loud, not hang
    }
  }
  __syncthreads();
  __builtin_amdgcn_sched_barrier(0);
}

// ---------------- weight conversion ----------------
// mode 0: plain f32->bf16. mode 1: per-16col-slice chunked for 512x512 W:
// elem (col,k) -> u16 off = (col>>4)*8192 + (k>>5)*512 + ((k>>3)&3)*128 + (col&15)*8 + (k&7)
#define NJOBS 22
struct Job { const void* base; int eoff; int n; int dstoff; int mode; };
struct Jobs { Job j[NJOBS]; };

__global__ __launch_bounds__(256) void k_convert(Jobs jobs, char* __restrict__ ws) {
  const Job jb = jobs.j[blockIdx.y];
  const int i0 = (blockIdx.x * 256 + threadIdx.x) * 8;
  if (i0 >= jb.n) return;
  u16* dst = (u16*)(ws + jb.dstoff);
  const float* src = (const float*)jb.base + jb.eoff;
  if (i0 + 8 <= jb.n) {
    const float4 a = *(const float4*)(src + i0);
    const float4 b = *(const float4*)(src + i0 + 4);
    u16 o[8] = {f2bf(a.x), f2bf(a.y), f2bf(a.z), f2bf(a.w),
                f2bf(b.x), f2bf(b.y), f2bf(b.z), f2bf(b.w)};
    int off = i0;
    if (jb.mode == 1) {
      const int col = i0 >> 9, k0 = i0 & 511;
      off = (col >> 4) * 8192 + (k0 >> 5) * 512 + ((k0 >> 3) & 3) * 128 + (col & 15) * 8;
    }
    *(uint4*)(dst + off) = *(uint4*)o;
  } else {
    for (int k = i0; k < jb.n; ++k) dst[k] = f2bf(src[k]);
  }
}

// ---- per-wave streamed GEMM: wave owns 16 cols. Wg = block's 64KB region
// (4 slices x 16KB); wave uses slice wid. Chunk = 1KB = k-slice of 32 x 16 cols
// = ONE gl_lds16. Ring: 8 x 1KB per wave. Ledger: entering iter c, chunks
// c..c+7 in flight (8 loads). vmcnt(7) -> chunk c landed. ds_read+MFMA;
// lgkmcnt(0) -> reads done; restage slot c&7 with chunk c+8 (or next layer's
// c-8). Tail (no next): vmcnt(7,6,...,0) at c=8..15.
__device__ __forceinline__ void gemm16(const u16* A, const char* Wg, const char* Wn,
                                       u16* wb, const u16* bias, int wid, int lane,
                                       f32x4& acc) {
  const int rc = lane & 15, kb = lane >> 4;
  acc = (f32x4){0.f, 0.f, 0.f, 0.f};
  const char* gw = Wg + wid * 16384;
  const char* gn = Wn ? Wn + wid * 16384 : nullptr;
#pragma unroll
  for (int c = 0; c < 16; ++c) {
    const bool gnb = (gn != nullptr);
    if (gnb || c <= 8) asm volatile("s_waitcnt vmcnt(7)" ::: "memory");
    else if (c == 9)  asm volatile("s_waitcnt vmcnt(6)" ::: "memory");
    else if (c == 10) asm volatile("s_waitcnt vmcnt(5)" ::: "memory");
    else if (c == 11) asm volatile("s_waitcnt vmcnt(4)" ::: "memory");
    else if (c == 12) asm volatile("s_waitcnt vmcnt(3)" ::: "memory");
    else if (c == 13) asm volatile("s_waitcnt vmcnt(2)" ::: "memory");
    else if (c == 14) asm volatile("s_waitcnt vmcnt(1)" ::: "memory");
    else              asm volatile("s_waitcnt vmcnt(0)" ::: "memory");
    __builtin_amdgcn_sched_barrier(0);
    const u16* B = wb + (c & 7) * 512;
    const bf16x8 a = *(const bf16x8*)&A[rc * LSTR + c * 32 + kb * 8];
    const bf16x8 b0 = *(const bf16x8*)&B[kb * 128 + rc * 8];
    acc = MFMA(a, b0, acc);
    asm volatile("s_waitcnt lgkmcnt(0)" ::: "memory");  // slot's reads landed
    __builtin_amdgcn_sched_barrier(0);
    if (c < 8) gl_lds16(gw + (c + 8) * 1024 + lane * 16, wb + (c & 7) * 512);
    else if (gn) gl_lds16(gn + (c - 8) * 1024 + lane * 16, wb + (c & 7) * 512);
  }
  const float bv = bf2f(bias[wid * 16 + rc]);
#pragma unroll
  for (int r = 0; r < 4; ++r) acc[r] += bv;
}

// store wave's 16x16 result into LDS A at global-col positions
__device__ __forceinline__ void store_A(u16* A, int cb, int wid, int lane, const f32x4 acc) {
  const int cr = lane & 15, rb = (lane >> 4) * 4;
  const int col = cb + wid * 16 + cr;
#pragma unroll
  for (int r = 0; r < 4; ++r) A[(rb + r) * LSTR + col] = f2bf(acc[r]);
}

__device__ __forceinline__ void add_A(const u16* A, int cb, int wid, int lane, f32x4& acc) {
  const int cr = lane & 15, rb = (lane >> 4) * 4;
  const int col = cb + wid * 16 + cr;
#pragma unroll
  for (int r = 0; r < 4; ++r) acc[r] += bf2f(A[(rb + r) * LSTR + col]);
}

__device__ __forceinline__ void add_glb_f32(const float* g, int cb, int wid, int lane,
                                            f32x4& acc) {
  const int cr = lane & 15, rb = (lane >> 4) * 4;
  const int col = cb + wid * 16 + cr;
#pragma unroll
  for (int r = 0; r < 4; ++r) acc[r] += g[(size_t)(rb + r) * 512 + col];
}

// block's 16x64 slice of A -> act (sc0 sc1 coherent stores); tid<128
__device__ __forceinline__ void slice_store(u16* act, const u16* A, int r0, int cb, int tid) {
  if (tid < 128) {
    const int r = tid >> 3, c8 = (tid & 7) * 8;
    u32x4 v = *(const u32x4*)&A[r * LSTR + cb + c8];
    st16_cc(act + (size_t)(r0 + r) * 512 + cb + c8, v);
  }
}

// full 16x512 rows act -> A via coherent loads (batched, one vmcnt)
__device__ __forceinline__ void load_act(const u16* act, u16* A, int r0, int tid) {
  const u16* base = act + (size_t)r0 * 512;
  const int i0 = tid, i1 = tid + 256, i2 = tid + 512, i3 = tid + 768;
  const void* p0 = base + (i0 >> 6) * 512 + (i0 & 63) * 8;
  const void* p1 = base + (i1 >> 6) * 512 + (i1 & 63) * 8;
  const void* p2 = base + (i2 >> 6) * 512 + (i2 & 63) * 8;
  const void* p3 = base + (i3 >> 6) * 512 + (i3 & 63) * 8;
  u32x4 d0, d1, d2, d3;
  asm volatile(
      "global_load_dwordx4 %0, %4, off sc0 sc1\n\t"
      "global_load_dwordx4 %1, %5, off sc0 sc1\n\t"
      "global_load_dwordx4 %2, %6, off sc0 sc1\n\t"
      "global_load_dwordx4 %3, %7, off sc0 sc1\n\t"
      "s_waitcnt vmcnt(0)"
      : "=&v"(d0), "=&v"(d1), "=&v"(d2), "=&v"(d3)
      : "v"(p0), "v"(p1), "v"(p2), "v"(p3)
      : "memory");
  *(u32x4*)&A[(i0 >> 6) * LSTR + (i0 & 63) * 8] = d0;
  *(u32x4*)&A[(i1 >> 6) * LSTR + (i1 & 63) * 8] = d1;
  *(u32x4*)&A[(i2 >> 6) * LSTR + (i2 & 63) * 8] = d2;
  *(u32x4*)&A[(i3 >> 6) * LSTR + (i3 & 63) * 8] = d3;
}

// LayerNorm in place on A: wave wid handles rows wid*4..wid*4+3 (full 512 cols)
__device__ __forceinline__ void ln4(u16* A, const u16* g, const u16* b, int wid, int lane) {
#pragma unroll
  for (int rr = 0; rr < 4; ++rr) {
    const int row = wid * 4 + rr;
    float s = 0.f, q = 0.f;
#pragma unroll
    for (int c = lane; c < 512; c += 64) {
      const float v = bf2f(A[row * LSTR + c]);
      s += v; q += v * v;
    }
#pragma unroll
    for (int m = 1; m < 64; m <<= 1) {
      s += __shfl_xor(s, m, 64);
      q += __shfl_xor(q, m, 64);
    }
    const float mu = s * (1.f / 512.f);
    const float rs = rsqrtf(q * (1.f / 512.f) - mu * mu + 1e-5f);
#pragma unroll
    for (int c = lane; c < 512; c += 64) {
      const float v = (bf2f(A[row * LSTR + c]) - mu) * rs * bf2f(g[c]) + bf2f(b[c]);
      A[row * LSTR + c] = f2bf(v);
    }
  }
}

// ---- k_prot: pwr (8 pieces x 4 rot) from RAW f32. 32 blocks = j(4) x colgrp(8).
__global__ __launch_bounds__(256) void k_prot(const float* __restrict__ pemb,
                                              const float* __restrict__ rot_w,
                                              const float* __restrict__ rot_b,
                                              u16* __restrict__ pwr_ws) {
  __shared__ __align__(16) u16 A[16 * LSTR];
  const int tid = threadIdx.x, lane = tid & 63, wid = tid >> 6;
  const int j = blockIdx.x >> 3, g = blockIdx.x & 7;
  for (int idx = tid; idx < 16 * 64; idx += 256) {
    const int r = idx >> 6, c8 = (idx & 63) * 8;
    if (r < 8) {
      const float4 a = *(const float4*)(pemb + r * 512 + c8);
      const float4 b = *(const float4*)(pemb + r * 512 + c8 + 4);
      bf16x8 v = f8_to_bf(a, b);
      *(bf16x8*)&A[r * LSTR + c8] = v;
    } else {
      uint4 z = {0u, 0u, 0u, 0u};
      *(uint4*)&A[r * LSTR + c8] = z;
    }
  }
  __syncthreads();
  const int rc = lane & 15, kb = lane >> 4, rb = (lane >> 4) * 4;
  const int col = g * 64 + wid * 16 + rc;
  const bf16x8* ab = reinterpret_cast<const bf16x8*>(A) + rc * (LSTR / 8) + kb;
  const float* wf = rot_w + (size_t)(j * 512 + col) * 512 + kb * 8;
  f32x4 acc = (f32x4){0.f, 0.f, 0.f, 0.f};
#pragma unroll
  for (int ks = 0; ks < 16; ++ks) {
    const float4 w0 = *(const float4*)(wf + ks * 32);
    const float4 w1 = *(const float4*)(wf + ks * 32 + 4);
    acc = MFMA(ab[ks * 4], f8_to_bf(w0, w1), acc);
  }
  const float bv = rot_b[j * 512 + col];
#pragma unroll
  for (int r = 0; r < 4; ++r) {
    const int p = rb + r;
    if (p < 8) pwr_ws[(size_t)(p * 4 + j) * 512 + col] = f2bf(acc[r] + bv);
  }
}

// ---- k_pkv: kk/vv[32][512] f32 from pwr + RAW f32 k_w/v_w. 32 blocks.
__global__ __launch_bounds__(256) void k_pkv(const u16* __restrict__ pwr_ws,
                                             const float* __restrict__ k_w,
                                             const float* __restrict__ k_b,
                                             const float* __restrict__ v_w,
                                             const float* __restrict__ v_b,
                                             float* __restrict__ kk_ws,
                                             float* __restrict__ vv_ws) {
  __shared__ __align__(16) u16 A[32 * LSTR];
  const int tid = threadIdx.x, lane = tid & 63, wid = tid >> 6;
  const int t = blockIdx.x >> 4, g = blockIdx.x & 15;
  for (int idx = tid; idx < 32 * 64; idx += 256) {
    const int r = idx >> 6, c = idx & 63;
    *(uint4*)&A[r * LSTR + c * 8] = ((const uint4*)pwr_ws)[r * 64 + c];
  }
  __syncthreads();
  const float* W = t ? v_w : k_w;
  const float* Bb = t ? v_b : k_b;
  float* out = t ? vv_ws : kk_ws;
  const int rc = lane & 15, kb = lane >> 4, rb = (lane >> 4) * 4;
  const int rowt = wid >> 1;
  const int col = g * 32 + (wid & 1) * 16 + rc;
  const bf16x8* ab = reinterpret_cast<const bf16x8*>(A) + (rowt * 16 + rc) * (LSTR / 8) + kb;
  const float* wf = W + (size_t)col * 512 + kb * 8;
  f32x4 acc = (f32x4){0.f, 0.f, 0.f, 0.f};
#pragma unroll
  for (int ks = 0; ks < 16; ++ks) {
    const float4 w0 = *(const float4*)(wf + ks * 32);
    const float4 w1 = *(const float4*)(wf + ks * 32 + 4);
    acc = MFMA(ab[ks * 4], f8_to_bf(w0, w1), acc);
  }
  const float bv = Bb[col];
#pragma unroll
  for (int r = 0; r < 4; ++r)
    out[(size_t)(rowt * 16 + rb + r) * 512 + col] = acc[r] + bv;
}

// ---- main: 256 blocks (32 row-groups x 8 col-blocks of 64 cols) x 256 thr.
// idx = xcd + 8*bc + 64*hi (perf-only XCD grouping; correctness is sc1-based).
// Per-group barrier only; act via coherent (sc0 sc1) global buffer.
__global__ __launch_bounds__(256) void k_main(
    const float* __restrict__ state32, const float* __restrict__ mem32,
    const int* __restrict__ queue, char* __restrict__ ws,
    const float* __restrict__ kk_ws, const float* __restrict__ vv_ws,
    float* __restrict__ out_pol, float* __restrict__ out_val) {
  __shared__ __align__(16) u16 A[16 * LSTR];
  __shared__ __align__(16) u16 WB[4 * 8 * 512];  // 4 waves x (8 x 1KB ring)
  __shared__ int piece_s[16];
  __shared__ int qs_s;
  const int tid = threadIdx.x;
  const int lane = tid & 63, wid = tid >> 6;
  const int idx = blockIdx.x;
  const int xcd = idx & 7, bc = (idx >> 3) & 7, hi = idx >> 6;
  const int br = hi * 8 + xcd;           // row-group [0,32)
  const int r0 = br * 16, cb = bc * 64;
  u16* wb = &WB[wid * 4096];
  u16* act = (u16*)(ws + WS_ACT);
  int* grp = (int*)(ws + WS_CTR) + br * 32;  // 128B stride per group
  const int wofs = bc * 65536;           // block's 4-slice region in each weight

  const u16* a0v_b = (const u16*)(ws + WS_A0VB) + cb;
  const u16* a0o_b = (const u16*)(ws + WS_A0OB) + cb;
  const u16* q_b   = (const u16*)(ws + WS_QB) + cb;
  const u16* qkv_b = (const u16*)(ws + WS_QKVB) + cb;
  const u16* que_b = (const u16*)(ws + WS_QUEB) + cb;
  const u16* a1v_b = (const u16*)(ws + WS_A1VB) + cb;
  const u16* a1o_b = (const u16*)(ws + WS_A1OB) + cb;
  const u16* val_b = (const u16*)(ws + WS_VALB) + cb;
  const u16* pol_w = (const u16*)(ws + WS_POL);
  const u16* pol_b = (const u16*)(ws + WS_POLB);
  const u16* an_g = (const u16*)(ws + WS_ANG);  const u16* an_b = (const u16*)(ws + WS_ANB);
  const u16* fn_g = (const u16*)(ws + WS_FNG);  const u16* fn_b = (const u16*)(ws + WS_FNB);

  // start L1 DMA stream: chunks 0..7 per wave
  {
    const char* g0 = ws + WS_A0V + wofs + wid * 16384;
#pragma unroll
    for (int s = 0; s < 8; ++s) gl_lds16(g0 + s * 1024 + lane * 16, wb + s * 512);
  }
  // state f32 -> A bf16 (16x512)
  for (int i = tid; i < 1024; i += 256) {
    const int r = i >> 6, c8 = (i & 63) * 8;
    const float* src = state32 + (size_t)(r0 + r) * 512 + c8;
    const float4 a = *(const float4*)src;
    const float4 b = *(const float4*)(src + 4);
    bf16x8 v = f8_to_bf(a, b);
    *(bf16x8*)&A[r * LSTR + c8] = v;
  }
  if (tid == 0) {  // int64-vs-int32 probe
    int odd = 0;
    for (int i = 1; i < 128; i += 2) odd += (queue[i] != 0);
    qs_s = (odd == 0) ? 2 : 1;
  }
  __syncthreads();
  if (tid < 16) piece_s[tid] = queue[(size_t)(r0 + tid) * 5 * qs_s] & 7;
  // piece_s consumed after L1..L3 barriers -> ordering safe.

  f32x4 acc, res;
  // L1: v0 = state @ a0v^T
  gemm16(A, ws + WS_A0V + wofs, ws + WS_A0O + wofs, wb, a0v_b, wid, lane, acc);
  __syncthreads();  // all waves done reading A
  store_A(A, cb, wid, lane, acc);
  __syncthreads();
  slice_store(act, A, r0, cb, tid);
  gridbar(grp, 8 * 1, tid);
  load_act(act, A, r0, tid);
  __syncthreads();
  // L2: s0 = v0 @ a0o^T (residual to regs)
  gemm16(A, ws + WS_A0O + wofs, ws + WS_QW + wofs, wb, a0o_b, wid, lane, acc);
  res = acc;
  __syncthreads();
  store_A(A, cb, wid, lane, acc);
  __syncthreads();
  slice_store(act, A, r0, cb, tid);
  gridbar(grp, 8 * 2, tid);
  load_act(act, A, r0, tid);
  __syncthreads();
  // L3: qv = s0 @ q_w^T -> A slice; attention head h=bc (col-local)
  gemm16(A, ws + WS_QW + wofs, ws + WS_QKV + wofs, wb, q_b, wid, lane, acc);
  __syncthreads();
  store_A(A, cb, wid, lane, acc);
  __syncthreads();
  if (tid < 16) {  // row r, head h=bc: cols h*64..h*64+63 == block slice
    const int r = tid, h = bc;
    const int p = piece_s[r];
    const u16* qrow = &A[r * LSTR + h * 64];
    const float* kkp = kk_ws + (size_t)(p * 4) * 512 + h * 64;
    const float* vvp = vv_ws + (size_t)(p * 4) * 512 + h * 64;
    float lg[4];
#pragma unroll
    for (int jj = 0; jj < 4; ++jj) {
      float s = 0.f;
      const float* kj = kkp + jj * 512;
#pragma unroll
      for (int d = 0; d < 64; d += 4) {
        const float4 kv = *(const float4*)(kj + d);
        s += bf2f(qrow[d]) * kv.x + bf2f(qrow[d + 1]) * kv.y + bf2f(qrow[d + 2]) * kv.z +
             bf2f(qrow[d + 3]) * kv.w;
      }
      lg[jj] = s * 0.125f;
    }
    const float m = fmaxf(fmaxf(lg[0], lg[1]), fmaxf(lg[2], lg[3]));
    float e0 = __expf(lg[0] - m), e1 = __expf(lg[1] - m);
    float e2 = __expf(lg[2] - m), e3 = __expf(lg[3] - m);
    const float inv = 1.f / (e0 + e1 + e2 + e3);
    e0 *= inv; e1 *= inv; e2 *= inv; e3 *= inv;
    u16* orow = &A[r * LSTR + h * 64];
#pragma unroll
    for (int d = 0; d < 64; d += 4) {
      const float4 v0 = *(const float4*)(vvp + 0 * 512 + d);
      const float4 v1 = *(const float4*)(vvp + 1 * 512 + d);
      const float4 v2 = *(const float4*)(vvp + 2 * 512 + d);
      const float4 v3 = *(const float4*)(vvp + 3 * 512 + d);
      orow[d + 0] = f2bf(e0 * v0.x + e1 * v1.x + e2 * v2.x + e3 * v3.x);
      orow[d + 1] = f2bf(e0 * v0.y + e1 * v1.y + e2 * v2.y + e3 * v3.y);
      orow[d + 2] = f2bf(e0 * v0.z + e1 * v1.z + e2 * v2.z + e3 * v3.z);
      orow[d + 3] = f2bf(e0 * v0.w + e1 * v1.w + e2 * v2.w + e3 * v3.w);
    }
  }
  __syncthreads();
  slice_store(act, A, r0, cb, tid);
  gridbar(grp, 8 * 3, tid);
  load_act(act, A, r0, tid);
  __syncthreads();
  // L4: x1 = s0(res) + attn @ qkv^T
  gemm16(A, ws + WS_QKV + wofs, ws + WS_QUE + wofs, wb, qkv_b, wid, lane, acc);
  acc += res;
  __syncthreads();
  store_A(A, cb, wid, lane, acc);
  __syncthreads();
  slice_store(act, A, r0, cb, tid);
  gridbar(grp, 8 * 4, tid);
  load_act(act, A, r0, tid);
  __syncthreads();
  ln4(A, an_g, an_b, wid, lane);  // s1
  __syncthreads();
  // L5: x2 = s1 + s1 @ que_w^T
  gemm16(A, ws + WS_QUE + wofs, ws + WS_A1V + wofs, wb, que_b, wid, lane, acc);
  add_A(A, cb, wid, lane, acc);
  __syncthreads();
  store_A(A, cb, wid, lane, acc);
  __syncthreads();
  slice_store(act, A, r0, cb, tid);
  gridbar(grp, 8 * 5, tid);
  load_act(act, A, r0, tid);
  __syncthreads();
  ln4(A, fn_g, fn_b, wid, lane);  // s2
  __syncthreads();
  // L6: v1 = s2 @ a1v^T
  gemm16(A, ws + WS_A1V + wofs, ws + WS_A1O + wofs, wb, a1v_b, wid, lane, acc);
  __syncthreads();
  store_A(A, cb, wid, lane, acc);
  __syncthreads();
  slice_store(act, A, r0, cb, tid);
  gridbar(grp, 8 * 6, tid);
  load_act(act, A, r0, tid);
  __syncthreads();
  // L7: xo = v1 @ a1o^T + memory
  gemm16(A, ws + WS_A1O + wofs, ws + WS_VAL + wofs, wb, a1o_b, wid, lane, acc);
  add_glb_f32(mem32 + (size_t)r0 * 512, cb, wid, lane, acc);
  __syncthreads();
  store_A(A, cb, wid, lane, acc);
  __syncthreads();
  slice_store(act, A, r0, cb, tid);
  gridbar(grp, 8 * 7, tid);
  load_act(act, A, r0, tid);  // xo full rows
  __syncthreads();
  // L8: val = xo @ val_w^T -> out (f32)
  gemm16(A, ws + WS_VAL + wofs, nullptr, wb, val_b, wid, lane, acc);
  {
    const int cr = lane & 15, rb = (lane >> 4) * 4;
    const int col = cb + wid * 16 + cr;
#pragma unroll
    for (int r = 0; r < 4; ++r) out_val[(size_t)(r0 + rb + r) * 512 + col] = acc[r];
  }
  // L9: pol (10 cols) - bc==0 blocks, wave 0 (xo full rows still in A)
  if (bc == 0 && wid == 0) {
    const int rc = lane & 15, kb = lane >> 4;
    const int wrow = rc < 10 ? rc : 0;
    const bf16x8* ab = reinterpret_cast<const bf16x8*>(A) + rc * (LSTR / 8) + kb;
    const bf16x8* wbp = reinterpret_cast<const bf16x8*>(pol_w) + wrow * 64 + kb;
    f32x4 pa = (f32x4){0.f, 0.f, 0.f, 0.f};
#pragma unroll
    for (int ks = 0; ks < 16; ++ks) pa = MFMA(ab[ks * 4], wbp[ks * 4], pa);
    if (rc < 10) {
      const float bv = bf2f(pol_b[rc]);
      const int rb = (lane >> 4) * 4;
#pragma unroll
      for (int r = 0; r < 4; ++r) out_pol[(size_t)(r0 + rb + r) * 10 + rc] = pa[r] + bv;
    }
  }
}

extern "C" void kernel_launch(void* const* d_in, const int* in_sizes, int n_in, void* d_out,
                              int out_size, void* d_ws, size_t ws_size, hipStream_t stream) {
  (void)in_sizes; (void)n_in; (void)out_size; (void)ws_size;
  char* ws = (char*)d_ws;

  Jobs jobs;
  int ji = 0;
  auto add = [&](int idx, int eoff, int n, int off, int mode) {
    jobs.j[ji].base = d_in[idx]; jobs.j[ji].eoff = eoff; jobs.j[ji].n = n;
    jobs.j[ji].dstoff = off; jobs.j[ji].mode = mode; ++ji;
  };
  add(38, 524288, 262144, WS_A0V, 1);   // a0_in_w rows [1024:1536] (v-slice)
  add(40, 0, 262144, WS_A0O, 1);
  add(12, 0, 262144, WS_QW, 1);
  add(18, 0, 262144, WS_QKV, 1);
  add(20, 0, 262144, WS_QUE, 1);
  add(42, 524288, 262144, WS_A1V, 1);   // a1_in_w rows [1024:1536]
  add(44, 0, 262144, WS_A1O, 1);
  add(48, 0, 262144, WS_VAL, 1);
  add(46, 0, 5120, WS_POL, 0);
  add(39, 1024, 512, WS_A0VB, 0);
  add(41, 0, 512, WS_A0OB, 0);
  add(13, 0, 512, WS_QB, 0);
  add(19, 0, 512, WS_QKVB, 0);
  add(21, 0, 512, WS_QUEB, 0);
  add(43, 1024, 512, WS_A1VB, 0);
  add(45, 0, 512, WS_A1OB, 0);
  add(49, 0, 512, WS_VALB, 0);
  add(22, 0, 512, WS_ANG, 0);
  add(23, 0, 512, WS_ANB, 0);
  add(24, 0, 512, WS_FNG, 0);
  add(25, 0, 512, WS_FNB, 0);
  add(47, 0, 10, WS_POLB, 0);

  hipMemsetAsync(ws + WS_CTR, 0, 4096, stream);  // reset group counters per launch
  k_convert<<<dim3(128, NJOBS), dim3(256), 0, stream>>>(jobs, ws);
  k_prot<<<dim3(32), dim3(256), 0, stream>>>((const float*)d_in[9], (const float*)d_in[10],
                                             (const float*)d_in[11], (u16*)(ws + WS_PWR));
  k_pkv<<<dim3(32), dim3(256), 0, stream>>>((const u16*)(ws + WS_PWR), (const float*)d_in[14],
                                            (const float*)d_in[15], (const float*)d_in[16],
                                            (const float*)d_in[17], (float*)(ws + WS_KK),
                                            (float*)(ws + WS_VV));

  float* out_pol = (float*)d_out;
  float* out_val = out_pol + 512 * 10;
  k_main<<<dim3(256), dim3(256), 0, stream>>>(
      (const float*)d_in[3], (const float*)d_in[4], (const int*)d_in[1], ws,
      (const float*)(ws + WS_KK), (const float*)(ws + WS_VV), out_pol, out_val);
}

// Round 11
// 59.375 us; speedup vs baseline: 2.1014x; 1.1259x over previous
//
#include <hip/hip_runtime.h>

typedef unsigned short u16;
typedef __attribute__((ext_vector_type(8))) short bf16x8;
typedef __attribute__((ext_vector_type(4))) float f32x4;
typedef __attribute__((ext_vector_type(4))) unsigned int u32x4;

#define LSTR 520  // bf16 elems per LDS row: 512 + 8 pad

// ---------------- workspace layout (bytes) ----------------
#define WS_ACT     0          // 512x512 bf16 activations, sc0sc1-coherent
#define WS_A0V     524288
#define WS_A0O     1048576
#define WS_QW      1572864
#define WS_QKV     2097152
#define WS_QUE     2621440
#define WS_A1V     3145728
#define WS_A1O     3670016
#define WS_VAL     4194304
#define WS_POL     4718592
#define WS_PWR     7882752
#define WS_KK      7915520
#define WS_VV      7981056
#define WS_A0VB    8574976
#define WS_A0OB    (WS_A0VB + 1024)
#define WS_QB      (WS_A0VB + 2048)
#define WS_QKVB    (WS_A0VB + 5120)
#define WS_QUEB    (WS_A0VB + 6144)
#define WS_A1VB    (WS_A0VB + 7168)
#define WS_A1OB    (WS_A0VB + 8192)
#define WS_VALB    (WS_A0VB + 9216)
#define WS_ANG     (WS_A0VB + 10240)
#define WS_ANB     (WS_A0VB + 11264)
#define WS_FNG     (WS_A0VB + 12288)
#define WS_FNB     (WS_A0VB + 13312)
#define WS_POLB    (WS_A0VB + 14336)
#define WS_CTR     8650752    // 32 group counters x 128B, zeroed by k_convert

__device__ __forceinline__ float bf2f(u16 u) {
  union { unsigned int i; float f; } v; v.i = ((unsigned int)u) << 16; return v.f;
}
__device__ __forceinline__ u16 f2bf(float f) {
  union { float f; unsigned int i; } v; v.f = f;
  unsigned int r = v.i + 0x7fffu + ((v.i >> 16) & 1u);
  return (u16)(r >> 16);
}
__device__ __forceinline__ bf16x8 f8_to_bf(const float4 a, const float4 b) {
  u16 o[8] = {f2bf(a.x), f2bf(a.y), f2bf(a.z), f2bf(a.w),
              f2bf(b.x), f2bf(b.y), f2bf(b.z), f2bf(b.w)};
  return *(bf16x8*)o;
}
__device__ __forceinline__ f32x4 MFMA(bf16x8 a, bf16x8 b, f32x4 c) {
  return __builtin_amdgcn_mfma_f32_16x16x32_bf16(a, b, c, 0, 0, 0);
}
__device__ __forceinline__ void gl_lds16(const void* g, void* l) {
  __builtin_amdgcn_global_load_lds((const __attribute__((address_space(1))) void*)g,
                                   (__attribute__((address_space(3))) void*)l, 16, 0, 0);
}
__device__ __forceinline__ void st16_cc(void* p, u32x4 v) {
  asm volatile("global_store_dwordx4 %0, %1, off sc0 sc1" :: "v"(p), "v"(v) : "memory");
}

// ---- per-row-group barrier. VMN=8: wave's last-issued op (the 1 act store)
// retires while the 8 next-layer DMA prefetches stay in flight across the spin.
// VMN=0: full drain (needed when preceding phase consumed vmem loads, so the
// ring is already drained and outstanding==1 store only).
template <int VMN>
__device__ __forceinline__ void gridbar(int* grp, int target, int tid) {
  if (VMN == 8) asm volatile("s_waitcnt vmcnt(8)" ::: "memory");
  else          asm volatile("s_waitcnt vmcnt(0)" ::: "memory");
  __syncthreads();
  if (tid == 0) {
    __hip_atomic_fetch_add(grp, 1, __ATOMIC_RELAXED, __HIP_MEMORY_SCOPE_AGENT);
    int it = 0;
    while (__hip_atomic_load(grp, __ATOMIC_RELAXED, __HIP_MEMORY_SCOPE_AGENT) < target) {
      __builtin_amdgcn_s_sleep(2);
      if (++it > 2000000) break;  // bounded: fail loud, not hang
    }
  }
  __syncthreads();
  __builtin_amdgcn_sched_barrier(0);
}

// ---------------- weight conversion + prot + counter-zero ----------------
// mode 0: plain f32->bf16. mode 1: per-16col-slice chunked for 512x512 W:
// elem (col,k) -> u16 off = (col>>4)*8192 + (k>>5)*512 + ((k>>3)&3)*128 + (col&15)*8 + (k&7)
#define NJOBS 22
struct Job { const void* base; int eoff; int n; int dstoff; int mode; };
struct Jobs { Job j[NJOBS]; };

__global__ __launch_bounds__(256) void k_convert(Jobs jobs, char* __restrict__ ws,
                                                 const float* __restrict__ pemb,
                                                 const float* __restrict__ rot_w,
                                                 const float* __restrict__ rot_b,
                                                 u16* __restrict__ pwr_ws) {
  const int tid = threadIdx.x;
  if (blockIdx.y == NJOBS) {
    // counter zeroing (block x==0) + prot (blocks x<32 = j(4) x colgrp(8))
    if (blockIdx.x == 0) {
      u32x4 z = {0u, 0u, 0u, 0u};
      ((u32x4*)(ws + WS_CTR))[tid] = z;
    }
    if (blockIdx.x >= 32) return;
    __shared__ __align__(16) u16 A[16 * LSTR];
    const int lane = tid & 63, wid = tid >> 6;
    const int j = blockIdx.x >> 3, g = blockIdx.x & 7;
    for (int idx = tid; idx < 16 * 64; idx += 256) {
      const int r = idx >> 6, c8 = (idx & 63) * 8;
      if (r < 8) {
        const float4 a = *(const float4*)(pemb + r * 512 + c8);
        const float4 b = *(const float4*)(pemb + r * 512 + c8 + 4);
        bf16x8 v = f8_to_bf(a, b);
        *(bf16x8*)&A[r * LSTR + c8] = v;
      } else {
        uint4 z = {0u, 0u, 0u, 0u};
        *(uint4*)&A[r * LSTR + c8] = z;
      }
    }
    __syncthreads();
    const int rc = lane & 15, kb = lane >> 4, rb = (lane >> 4) * 4;
    const int col = g * 64 + wid * 16 + rc;
    const bf16x8* ab = reinterpret_cast<const bf16x8*>(A) + rc * (LSTR / 8) + kb;
    const float* wf = rot_w + (size_t)(j * 512 + col) * 512 + kb * 8;
    f32x4 acc = (f32x4){0.f, 0.f, 0.f, 0.f};
#pragma unroll
    for (int ks = 0; ks < 16; ++ks) {
      const float4 w0 = *(const float4*)(wf + ks * 32);
      const float4 w1 = *(const float4*)(wf + ks * 32 + 4);
      acc = MFMA(ab[ks * 4], f8_to_bf(w0, w1), acc);
    }
    const float bv = rot_b[j * 512 + col];
#pragma unroll
    for (int r = 0; r < 4; ++r) {
      const int p = rb + r;
      if (p < 8) pwr_ws[(size_t)(p * 4 + j) * 512 + col] = f2bf(acc[r] + bv);
    }
    return;
  }
  const Job jb = jobs.j[blockIdx.y];
  const int i0 = (blockIdx.x * 256 + tid) * 8;
  if (i0 >= jb.n) return;
  u16* dst = (u16*)(ws + jb.dstoff);
  const float* src = (const float*)jb.base + jb.eoff;
  if (i0 + 8 <= jb.n) {
    const float4 a = *(const float4*)(src + i0);
    const float4 b = *(const float4*)(src + i0 + 4);
    u16 o[8] = {f2bf(a.x), f2bf(a.y), f2bf(a.z), f2bf(a.w),
                f2bf(b.x), f2bf(b.y), f2bf(b.z), f2bf(b.w)};
    int off = i0;
    if (jb.mode == 1) {
      const int col = i0 >> 9, k0 = i0 & 511;
      off = (col >> 4) * 8192 + (k0 >> 5) * 512 + ((k0 >> 3) & 3) * 128 + (col & 15) * 8;
    }
    *(uint4*)(dst + off) = *(uint4*)o;
  } else {
    for (int k = i0; k < jb.n; ++k) dst[k] = f2bf(src[k]);
  }
}

// ---- pipelined per-wave streamed GEMM: wave owns 16 cols; ring 8 x 1KB.
// Entry invariant: ring holds this layer's chunks 0..7 (issued, maybe landed).
// A-fragments preloaded to regs; 3-deep B-read pipeline. Restage slot c&7 at
// iter c with this layer's chunk c+8 (c<8) or next layer's chunk c-8 (gn).
// vmcnt ledger: steady vmcnt(5) (chunk c+3 landed); no-gn tail 4,3,2,1,0 at
// c=8..12. lgkm: lgkmcnt(2) after each B-read issue; 1 at c=13, 0 at c=14.
__device__ __forceinline__ void gemm16(const u16* A, const char* Wg, const char* Wn,
                                       u16* wb, const u16* bias, int wid, int lane,
                                       f32x4& acc) {
  const int rc = lane & 15, kb = lane >> 4;
  const char* gw = Wg + wid * 16384;
  const char* gn = Wn ? Wn + wid * 16384 : nullptr;
  bf16x8 a[16];
#pragma unroll
  for (int c = 0; c < 16; ++c) a[c] = *(const bf16x8*)&A[rc * LSTR + c * 32 + kb * 8];
  asm volatile("s_waitcnt vmcnt(5)" ::: "memory");  // chunks 0..2 landed
  __builtin_amdgcn_sched_barrier(0);
  bf16x8 bq[3];
  bq[0] = *(const bf16x8*)&wb[0 * 512 + kb * 128 + rc * 8];
  bq[1] = *(const bf16x8*)&wb[1 * 512 + kb * 128 + rc * 8];
  bq[2] = *(const bf16x8*)&wb[2 * 512 + kb * 128 + rc * 8];
  asm volatile("s_waitcnt lgkmcnt(0)" ::: "memory");  // a[] + b0..b2 in regs
  __builtin_amdgcn_sched_barrier(0);
  acc = (f32x4){0.f, 0.f, 0.f, 0.f};
#pragma unroll
  for (int c = 0; c < 16; ++c) {
    acc = MFMA(a[c], bq[c % 3], acc);
    if (c < 8) gl_lds16(gw + (c + 8) * 1024 + lane * 16, wb + (c & 7) * 512);
    else if (gn) gl_lds16(gn + (c - 8) * 1024 + lane * 16, wb + (c & 7) * 512);
    if (c <= 12) {
      if (gn || c <= 7)  { asm volatile("s_waitcnt vmcnt(5)" ::: "memory"); }
      else if (c == 8)   { asm volatile("s_waitcnt vmcnt(4)" ::: "memory"); }
      else if (c == 9)   { asm volatile("s_waitcnt vmcnt(3)" ::: "memory"); }
      else if (c == 10)  { asm volatile("s_waitcnt vmcnt(2)" ::: "memory"); }
      else if (c == 11)  { asm volatile("s_waitcnt vmcnt(1)" ::: "memory"); }
      else               { asm volatile("s_waitcnt vmcnt(0)" ::: "memory"); }
      __builtin_amdgcn_sched_barrier(0);
      bq[c % 3] = *(const bf16x8*)&wb[((c + 3) & 7) * 512 + kb * 128 + rc * 8];
      asm volatile("s_waitcnt lgkmcnt(2)" ::: "memory");  // b[c+1] in reg
    } else if (c == 13) {
      asm volatile("s_waitcnt lgkmcnt(1)" ::: "memory");  // b[14] in reg
    } else if (c == 14) {
      asm volatile("s_waitcnt lgkmcnt(0)" ::: "memory");  // b[15] in reg
    }
    __builtin_amdgcn_sched_barrier(0);
  }
  const float bv = bf2f(bias[wid * 16 + rc]);
#pragma unroll
  for (int r = 0; r < 4; ++r) acc[r] += bv;
}

__device__ __forceinline__ void store_A(u16* A, int cb, int wid, int lane, const f32x4 acc) {
  const int cr = lane & 15, rb = (lane >> 4) * 4;
  const int col = cb + wid * 16 + cr;
#pragma unroll
  for (int r = 0; r < 4; ++r) A[(rb + r) * LSTR + col] = f2bf(acc[r]);
}

__device__ __forceinline__ void add_A(const u16* A, int cb, int wid, int lane, f32x4& acc) {
  const int cr = lane & 15, rb = (lane >> 4) * 4;
  const int col = cb + wid * 16 + cr;
#pragma unroll
  for (int r = 0; r < 4; ++r) acc[r] += bf2f(A[(rb + r) * LSTR + col]);
}

__device__ __forceinline__ void add_glb_f32(const float* g, int cb, int wid, int lane,
                                            f32x4& acc) {
  const int cr = lane & 15, rb = (lane >> 4) * 4;
  const int col = cb + wid * 16 + cr;
#pragma unroll
  for (int r = 0; r < 4; ++r) acc[r] += g[(size_t)(rb + r) * 512 + col];
}

__device__ __forceinline__ void slice_store(u16* act, const u16* A, int r0, int cb, int tid) {
  if (tid < 128) {
    const int r = tid >> 3, c8 = (tid & 7) * 8;
    u32x4 v = *(const u32x4*)&A[r * LSTR + cb + c8];
    st16_cc(act + (size_t)(r0 + r) * 512 + cb + c8, v);
  }
}

__device__ __forceinline__ void load_act(const u16* act, u16* A, int r0, int tid) {
  const u16* base = act + (size_t)r0 * 512;
  const int i0 = tid, i1 = tid + 256, i2 = tid + 512, i3 = tid + 768;
  const void* p0 = base + (i0 >> 6) * 512 + (i0 & 63) * 8;
  const void* p1 = base + (i1 >> 6) * 512 + (i1 & 63) * 8;
  const void* p2 = base + (i2 >> 6) * 512 + (i2 & 63) * 8;
  const void* p3 = base + (i3 >> 6) * 512 + (i3 & 63) * 8;
  u32x4 d0, d1, d2, d3;
  asm volatile(
      "global_load_dwordx4 %0, %4, off sc0 sc1\n\t"
      "global_load_dwordx4 %1, %5, off sc0 sc1\n\t"
      "global_load_dwordx4 %2, %6, off sc0 sc1\n\t"
      "global_load_dwordx4 %3, %7, off sc0 sc1\n\t"
      "s_waitcnt vmcnt(0)"
      : "=&v"(d0), "=&v"(d1), "=&v"(d2), "=&v"(d3)
      : "v"(p0), "v"(p1), "v"(p2), "v"(p3)
      : "memory");
  *(u32x4*)&A[(i0 >> 6) * LSTR + (i0 & 63) * 8] = d0;
  *(u32x4*)&A[(i1 >> 6) * LSTR + (i1 & 63) * 8] = d1;
  *(u32x4*)&A[(i2 >> 6) * LSTR + (i2 & 63) * 8] = d2;
  *(u32x4*)&A[(i3 >> 6) * LSTR + (i3 & 63) * 8] = d3;
}

__device__ __forceinline__ void ln4(u16* A, const u16* g, const u16* b, int wid, int lane) {
#pragma unroll
  for (int rr = 0; rr < 4; ++rr) {
    const int row = wid * 4 + rr;
    float s = 0.f, q = 0.f;
#pragma unroll
    for (int c = lane; c < 512; c += 64) {
      const float v = bf2f(A[row * LSTR + c]);
      s += v; q += v * v;
    }
#pragma unroll
    for (int m = 1; m < 64; m <<= 1) {
      s += __shfl_xor(s, m, 64);
      q += __shfl_xor(q, m, 64);
    }
    const float mu = s * (1.f / 512.f);
    const float rs = rsqrtf(q * (1.f / 512.f) - mu * mu + 1e-5f);
#pragma unroll
    for (int c = lane; c < 512; c += 64) {
      const float v = (bf2f(A[row * LSTR + c]) - mu) * rs * bf2f(g[c]) + bf2f(b[c]);
      A[row * LSTR + c] = f2bf(v);
    }
  }
}

// ---- k_pkv: kk/vv[32][512] f32 from pwr + RAW f32 k_w/v_w. 32 blocks.
__global__ __launch_bounds__(256) void k_pkv(const u16* __restrict__ pwr_ws,
                                             const float* __restrict__ k_w,
                                             const float* __restrict__ k_b,
                                             const float* __restrict__ v_w,
                                             const float* __restrict__ v_b,
                                             float* __restrict__ kk_ws,
                                             float* __restrict__ vv_ws) {
  __shared__ __align__(16) u16 A[32 * LSTR];
  const int tid = threadIdx.x, lane = tid & 63, wid = tid >> 6;
  const int t = blockIdx.x >> 4, g = blockIdx.x & 15;
  for (int idx = tid; idx < 32 * 64; idx += 256) {
    const int r = idx >> 6, c = idx & 63;
    *(uint4*)&A[r * LSTR + c * 8] = ((const uint4*)pwr_ws)[r * 64 + c];
  }
  __syncthreads();
  const float* W = t ? v_w : k_w;
  const float* Bb = t ? v_b : k_b;
  float* out = t ? vv_ws : kk_ws;
  const int rc = lane & 15, kb = lane >> 4, rb = (lane >> 4) * 4;
  const int rowt = wid >> 1;
  const int col = g * 32 + (wid & 1) * 16 + rc;
  const bf16x8* ab = reinterpret_cast<const bf16x8*>(A) + (rowt * 16 + rc) * (LSTR / 8) + kb;
  const float* wf = W + (size_t)col * 512 + kb * 8;
  f32x4 acc = (f32x4){0.f, 0.f, 0.f, 0.f};
#pragma unroll
  for (int ks = 0; ks < 16; ++ks) {
    const float4 w0 = *(const float4*)(wf + ks * 32);
    const float4 w1 = *(const float4*)(wf + ks * 32 + 4);
    acc = MFMA(ab[ks * 4], f8_to_bf(w0, w1), acc);
  }
  const float bv = Bb[col];
#pragma unroll
  for (int r = 0; r < 4; ++r)
    out[(size_t)(rowt * 16 + rb + r) * 512 + col] = acc[r] + bv;
}

// ---- main: 256 blocks (32 row-groups x 8 col-blocks of 64 cols) x 256 thr.
__global__ __launch_bounds__(256) void k_main(
    const float* __restrict__ state32, const float* __restrict__ mem32,
    const int* __restrict__ queue, char* __restrict__ ws,
    const float* __restrict__ kk_ws, const float* __restrict__ vv_ws,
    float* __restrict__ out_pol, float* __restrict__ out_val) {
  __shared__ __align__(16) u16 A[16 * LSTR];
  __shared__ __align__(16) u16 WB[4 * 8 * 512];  // 4 waves x (8 x 1KB ring)
  __shared__ int piece_s[16];
  __shared__ int qs_s;
  const int tid = threadIdx.x;
  const int lane = tid & 63, wid = tid >> 6;
  const int idx = blockIdx.x;
  const int xcd = idx & 7, bc = (idx >> 3) & 7, hi = idx >> 6;
  const int br = hi * 8 + xcd;
  const int r0 = br * 16, cb = bc * 64;
  u16* wb = &WB[wid * 4096];
  u16* act = (u16*)(ws + WS_ACT);
  int* grp = (int*)(ws + WS_CTR) + br * 32;
  const int wofs = bc * 65536;

  const u16* a0v_b = (const u16*)(ws + WS_A0VB) + cb;
  const u16* a0o_b = (const u16*)(ws + WS_A0OB) + cb;
  const u16* q_b   = (const u16*)(ws + WS_QB) + cb;
  const u16* qkv_b = (const u16*)(ws + WS_QKVB) + cb;
  const u16* que_b = (const u16*)(ws + WS_QUEB) + cb;
  const u16* a1v_b = (const u16*)(ws + WS_A1VB) + cb;
  const u16* a1o_b = (const u16*)(ws + WS_A1OB) + cb;
  const u16* val_b = (const u16*)(ws + WS_VALB) + cb;
  const u16* pol_w = (const u16*)(ws + WS_POL);
  const u16* pol_b = (const u16*)(ws + WS_POLB);
  const u16* an_g = (const u16*)(ws + WS_ANG);  const u16* an_b = (const u16*)(ws + WS_ANB);
  const u16* fn_g = (const u16*)(ws + WS_FNG);  const u16* fn_b = (const u16*)(ws + WS_FNB);

  // start L1 DMA stream: chunks 0..7 per wave
  {
    const char* g0 = ws + WS_A0V + wofs + wid * 16384;
#pragma unroll
    for (int s = 0; s < 8; ++s) gl_lds16(g0 + s * 1024 + lane * 16, wb + s * 512);
  }
  // state f32 -> A bf16 (16x512)
  for (int i = tid; i < 1024; i += 256) {
    const int r = i >> 6, c8 = (i & 63) * 8;
    const float* src = state32 + (size_t)(r0 + r) * 512 + c8;
    const float4 a = *(const float4*)src;
    const float4 b = *(const float4*)(src + 4);
    bf16x8 v = f8_to_bf(a, b);
    *(bf16x8*)&A[r * LSTR + c8] = v;
  }
  if (tid == 0) {
    int odd = 0;
    for (int i = 1; i < 128; i += 2) odd += (queue[i] != 0);
    qs_s = (odd == 0) ? 2 : 1;
  }
  __syncthreads();
  if (tid < 16) piece_s[tid] = queue[(size_t)(r0 + tid) * 5 * qs_s] & 7;

  f32x4 acc, res;
  // L1: v0 = state @ a0v^T
  gemm16(A, ws + WS_A0V + wofs, ws + WS_A0O + wofs, wb, a0v_b, wid, lane, acc);
  __syncthreads();
  store_A(A, cb, wid, lane, acc);
  __syncthreads();
  slice_store(act, A, r0, cb, tid);
  gridbar<8>(grp, 8 * 1, tid);
  load_act(act, A, r0, tid);
  __syncthreads();
  // L2: s0 = v0 @ a0o^T (residual to regs)
  gemm16(A, ws + WS_A0O + wofs, ws + WS_QW + wofs, wb, a0o_b, wid, lane, acc);
  res = acc;
  __syncthreads();
  store_A(A, cb, wid, lane, acc);
  __syncthreads();
  slice_store(act, A, r0, cb, tid);
  gridbar<8>(grp, 8 * 2, tid);
  load_act(act, A, r0, tid);
  __syncthreads();
  // L3: qv = s0 @ q_w^T -> A slice; attention head h=bc (col-local)
  gemm16(A, ws + WS_QW + wofs, ws + WS_QKV + wofs, wb, q_b, wid, lane, acc);
  __syncthreads();
  store_A(A, cb, wid, lane, acc);
  __syncthreads();
  if (tid < 16) {
    const int r = tid, h = bc;
    const int p = piece_s[r];
    const u16* qrow = &A[r * LSTR + h * 64];
    const float* kkp = kk_ws + (size_t)(p * 4) * 512 + h * 64;
    const float* vvp = vv_ws + (size_t)(p * 4) * 512 + h * 64;
    float lg[4];
#pragma unroll
    for (int jj = 0; jj < 4; ++jj) {
      float s = 0.f;
      const float* kj = kkp + jj * 512;
#pragma unroll
      for (int d = 0; d < 64; d += 4) {
        const float4 kv = *(const float4*)(kj + d);
        s += bf2f(qrow[d]) * kv.x + bf2f(qrow[d + 1]) * kv.y + bf2f(qrow[d + 2]) * kv.z +
             bf2f(qrow[d + 3]) * kv.w;
      }
      lg[jj] = s * 0.125f;
    }
    const float m = fmaxf(fmaxf(lg[0], lg[1]), fmaxf(lg[2], lg[3]));
    float e0 = __expf(lg[0] - m), e1 = __expf(lg[1] - m);
    float e2 = __expf(lg[2] - m), e3 = __expf(lg[3] - m);
    const float inv = 1.f / (e0 + e1 + e2 + e3);
    e0 *= inv; e1 *= inv; e2 *= inv; e3 *= inv;
    u16* orow = &A[r * LSTR + h * 64];
#pragma unroll
    for (int d = 0; d < 64; d += 4) {
      const float4 v0 = *(const float4*)(vvp + 0 * 512 + d);
      const float4 v1 = *(const float4*)(vvp + 1 * 512 + d);
      const float4 v2 = *(const float4*)(vvp + 2 * 512 + d);
      const float4 v3 = *(const float4*)(vvp + 3 * 512 + d);
      orow[d + 0] = f2bf(e0 * v0.x + e1 * v1.x + e2 * v2.x + e3 * v3.x);
      orow[d + 1] = f2bf(e0 * v0.y + e1 * v1.y + e2 * v2.y + e3 * v3.y);
      orow[d + 2] = f2bf(e0 * v0.z + e1 * v1.z + e2 * v2.z + e3 * v3.z);
      orow[d + 3] = f2bf(e0 * v0.w + e1 * v1.w + e2 * v2.w + e3 * v3.w);
    }
  }
  __syncthreads();
  slice_store(act, A, r0, cb, tid);
  gridbar<0>(grp, 8 * 3, tid);  // attention loads drained the ring -> full wait
  load_act(act, A, r0, tid);
  __syncthreads();
  // L4: x1 = s0(res) + attn @ qkv^T
  gemm16(A, ws + WS_QKV + wofs, ws + WS_QUE + wofs, wb, qkv_b, wid, lane, acc);
  acc += res;
  __syncthreads();
  store_A(A, cb, wid, lane, acc);
  __syncthreads();
  slice_store(act, A, r0, cb, tid);
  gridbar<8>(grp, 8 * 4, tid);
  load_act(act, A, r0, tid);
  __syncthreads();
  ln4(A, an_g, an_b, wid, lane);  // s1
  __syncthreads();
  // L5: x2 = s1 + s1 @ que_w^T
  gemm16(A, ws + WS_QUE + wofs, ws + WS_A1V + wofs, wb, que_b, wid, lane, acc);
  add_A(A, cb, wid, lane, acc);
  __syncthreads();
  store_A(A, cb, wid, lane, acc);
  __syncthreads();
  slice_store(act, A, r0, cb, tid);
  gridbar<8>(grp, 8 * 5, tid);
  load_act(act, A, r0, tid);
  __syncthreads();
  ln4(A, fn_g, fn_b, wid, lane);  // s2
  __syncthreads();
  // L6: v1 = s2 @ a1v^T
  gemm16(A, ws + WS_A1V + wofs, ws + WS_A1O + wofs, wb, a1v_b, wid, lane, acc);
  __syncthreads();
  store_A(A, cb, wid, lane, acc);
  __syncthreads();
  slice_store(act, A, r0, cb, tid);
  gridbar<8>(grp, 8 * 6, tid);
  load_act(act, A, r0, tid);
  __syncthreads();
  // L7: xo = v1 @ a1o^T + memory
  gemm16(A, ws + WS_A1O + wofs, ws + WS_VAL + wofs, wb, a1o_b, wid, lane, acc);
  add_glb_f32(mem32 + (size_t)r0 * 512, cb, wid, lane, acc);
  __syncthreads();
  store_A(A, cb, wid, lane, acc);
  __syncthreads();
  slice_store(act, A, r0, cb, tid);
  gridbar<0>(grp, 8 * 7, tid);  // memory-adds drained the ring -> full wait
  load_act(act, A, r0, tid);
  __syncthreads();
  // L8: val = xo @ val_w^T -> out (f32)
  gemm16(A, ws + WS_VAL + wofs, nullptr, wb, val_b, wid, lane, acc);
  {
    const int cr = lane & 15, rb = (lane >> 4) * 4;
    const int col = cb + wid * 16 + cr;
#pragma unroll
    for (int r = 0; r < 4; ++r) out_val[(size_t)(r0 + rb + r) * 512 + col] = acc[r];
  }
  // L9: pol (10 cols) - bc==0 blocks, wave 0 (xo full rows in A)
  if (bc == 0 && wid == 0) {
    const int rc = lane & 15, kb = lane >> 4;
    const int wrow = rc < 10 ? rc : 0;
    const bf16x8* ab = reinterpret_cast<const bf16x8*>(A) + rc * (LSTR / 8) + kb;
    const bf16x8* wbp = reinterpret_cast<const bf16x8*>(pol_w) + wrow * 64 + kb;
    f32x4 pa = (f32x4){0.f, 0.f, 0.f, 0.f};
#pragma unroll
    for (int ks = 0; ks < 16; ++ks) pa = MFMA(ab[ks * 4], wbp[ks * 4], pa);
    if (rc < 10) {
      const float bv = bf2f(pol_b[rc]);
      const int rb = (lane >> 4) * 4;
#pragma unroll
      for (int r = 0; r < 4; ++r) out_pol[(size_t)(r0 + rb + r) * 10 + rc] = pa[r] + bv;
    }
  }
}

extern "C" void kernel_launch(void* const* d_in, const int* in_sizes, int n_in, void* d_out,
                              int out_size, void* d_ws, size_t ws_size, hipStream_t stream) {
  (void)in_sizes; (void)n_in; (void)out_size; (void)ws_size;
  char* ws = (char*)d_ws;

  Jobs jobs;
  int ji = 0;
  auto add = [&](int idx, int eoff, int n, int off, int mode) {
    jobs.j[ji].base = d_in[idx]; jobs.j[ji].eoff = eoff; jobs.j[ji].n = n;
    jobs.j[ji].dstoff = off; jobs.j[ji].mode = mode; ++ji;
  };
  add(38, 524288, 262144, WS_A0V, 1);   // a0_in_w rows [1024:1536] (v-slice)
  add(40, 0, 262144, WS_A0O, 1);
  add(12, 0, 262144, WS_QW, 1);
  add(18, 0, 262144, WS_QKV, 1);
  add(20, 0, 262144, WS_QUE, 1);
  add(42, 524288, 262144, WS_A1V, 1);   // a1_in_w rows [1024:1536]
  add(44, 0, 262144, WS_A1O, 1);
  add(48, 0, 262144, WS_VAL, 1);
  add(46, 0, 5120, WS_POL, 0);
  add(39, 1024, 512, WS_A0VB, 0);
  add(41, 0, 512, WS_A0OB, 0);
  add(13, 0, 512, WS_QB, 0);
  add(19, 0, 512, WS_QKVB, 0);
  add(21, 0, 512, WS_QUEB, 0);
  add(43, 1024, 512, WS_A1VB, 0);
  add(45, 0, 512, WS_A1OB, 0);
  add(49, 0, 512, WS_VALB, 0);
  add(22, 0, 512, WS_ANG, 0);
  add(23, 0, 512, WS_ANB, 0);
  add(24, 0, 512, WS_FNG, 0);
  add(25, 0, 512, WS_FNB, 0);
  add(47, 0, 10, WS_POLB, 0);

  k_convert<<<dim3(128, NJOBS + 1), dim3(256), 0, stream>>>(
      jobs, ws, (const float*)d_in[9], (const float*)d_in[10], (const float*)d_in[11],
      (u16*)(ws + WS_PWR));
  k_pkv<<<dim3(32), dim3(256), 0, stream>>>((const u16*)(ws + WS_PWR), (const float*)d_in[14],
                                            (const float*)d_in[15], (const float*)d_in[16],
                                            (const float*)d_in[17], (float*)(ws + WS_KK),
                                            (float*)(ws + WS_VV));

  float* out_pol = (float*)d_out;
  float* out_val = out_pol + 512 * 10;
  k_main<<<dim3(256), dim3(256), 0, stream>>>(
      (const float*)d_in[3], (const float*)d_in[4], (const int*)d_in[1], ws,
      (const float*)(ws + WS_KK), (const float*)(ws + WS_VV), out_pol, out_val);
}

// Round 12
// 54.882 us; speedup vs baseline: 2.2735x; 1.0819x over previous
//
#include <hip/hip_runtime.h>

typedef unsigned short u16;
typedef __attribute__((ext_vector_type(8))) short bf16x8;
typedef __attribute__((ext_vector_type(4))) float f32x4;
typedef __attribute__((ext_vector_type(4))) unsigned int u32x4;

#define LSTR 520  // bf16 elems per LDS row: 512 + 8 pad

// ---------------- workspace layout (bytes) ----------------
#define WS_ACT     0          // 512x512 bf16 activations, sc0sc1-coherent
#define WS_A0V     524288
#define WS_A0O     1048576
#define WS_QW      1572864
#define WS_QKV     2097152
#define WS_QUE     2621440
#define WS_A1V     3145728
#define WS_A1O     3670016
#define WS_VAL     4194304
#define WS_POL     4718592
#define WS_PWR     7882752
#define WS_KK      7915520
#define WS_VV      7981056
#define WS_A0VB    8574976
#define WS_A0OB    (WS_A0VB + 1024)
#define WS_QB      (WS_A0VB + 2048)
#define WS_QKVB    (WS_A0VB + 5120)
#define WS_QUEB    (WS_A0VB + 6144)
#define WS_A1VB    (WS_A0VB + 7168)
#define WS_A1OB    (WS_A0VB + 8192)
#define WS_VALB    (WS_A0VB + 9216)
#define WS_ANG     (WS_A0VB + 10240)
#define WS_ANB     (WS_A0VB + 11264)
#define WS_FNG     (WS_A0VB + 12288)
#define WS_FNB     (WS_A0VB + 13312)
#define WS_POLB    (WS_A0VB + 14336)
#define WS_CTR     8650752    // 32 group counters x 128B, zeroed by k_convert

__device__ __forceinline__ float bf2f(u16 u) {
  union { unsigned int i; float f; } v; v.i = ((unsigned int)u) << 16; return v.f;
}
__device__ __forceinline__ u16 f2bf(float f) {
  union { float f; unsigned int i; } v; v.f = f;
  unsigned int r = v.i + 0x7fffu + ((v.i >> 16) & 1u);
  return (u16)(r >> 16);
}
__device__ __forceinline__ bf16x8 f8_to_bf(const float4 a, const float4 b) {
  u16 o[8] = {f2bf(a.x), f2bf(a.y), f2bf(a.z), f2bf(a.w),
              f2bf(b.x), f2bf(b.y), f2bf(b.z), f2bf(b.w)};
  return *(bf16x8*)o;
}
__device__ __forceinline__ f32x4 MFMA(bf16x8 a, bf16x8 b, f32x4 c) {
  return __builtin_amdgcn_mfma_f32_16x16x32_bf16(a, b, c, 0, 0, 0);
}
__device__ __forceinline__ void gl_lds16(const void* g, void* l) {
  __builtin_amdgcn_global_load_lds((const __attribute__((address_space(1))) void*)g,
                                   (__attribute__((address_space(3))) void*)l, 16, 0, 0);
}
__device__ __forceinline__ void st16_cc(void* p, u32x4 v) {
  asm volatile("global_store_dwordx4 %0, %1, off sc0 sc1" :: "v"(p), "v"(v) : "memory");
}

// ---- per-row-group barrier. At entry each wave has (oldest) 1 act store +
// (younger) 16 next-layer DMA loads outstanding. vmcnt(16) retires the store
// (in-order counter) while the 16 loads stay in flight across the spin.
__device__ __forceinline__ void gridbar(int* grp, int target, int tid) {
  asm volatile("s_waitcnt vmcnt(16)" ::: "memory");
  __syncthreads();
  if (tid == 0) {
    __hip_atomic_fetch_add(grp, 1, __ATOMIC_RELAXED, __HIP_MEMORY_SCOPE_AGENT);
    int it = 0;
    while (__hip_atomic_load(grp, __ATOMIC_RELAXED, __HIP_MEMORY_SCOPE_AGENT) < target) {
      __builtin_amdgcn_s_sleep(2);
      if (++it > 2000000) break;  // bounded: fail loud, not hang
    }
  }
  __syncthreads();
  __builtin_amdgcn_sched_barrier(0);
}

// ---------------- weight conversion + prot + counter-zero ----------------
// mode 0: plain f32->bf16. mode 1: per-16col-slice chunked for 512x512 W:
// elem (col,k) -> u16 off = (col>>4)*8192 + (k>>5)*512 + ((k>>3)&3)*128 + (col&15)*8 + (k&7)
#define NJOBS 22
struct Job { const void* base; int eoff; int n; int dstoff; int mode; };
struct Jobs { Job j[NJOBS]; };

__global__ __launch_bounds__(256) void k_convert(Jobs jobs, char* __restrict__ ws,
                                                 const float* __restrict__ pemb,
                                                 const float* __restrict__ rot_w,
                                                 const float* __restrict__ rot_b,
                                                 u16* __restrict__ pwr_ws) {
  const int tid = threadIdx.x;
  if (blockIdx.y == NJOBS) {
    if (blockIdx.x == 0) {
      u32x4 z = {0u, 0u, 0u, 0u};
      ((u32x4*)(ws + WS_CTR))[tid] = z;
    }
    if (blockIdx.x >= 32) return;
    __shared__ __align__(16) u16 A[16 * LSTR];
    const int lane = tid & 63, wid = tid >> 6;
    const int j = blockIdx.x >> 3, g = blockIdx.x & 7;
    for (int idx = tid; idx < 16 * 64; idx += 256) {
      const int r = idx >> 6, c8 = (idx & 63) * 8;
      if (r < 8) {
        const float4 a = *(const float4*)(pemb + r * 512 + c8);
        const float4 b = *(const float4*)(pemb + r * 512 + c8 + 4);
        bf16x8 v = f8_to_bf(a, b);
        *(bf16x8*)&A[r * LSTR + c8] = v;
      } else {
        uint4 z = {0u, 0u, 0u, 0u};
        *(uint4*)&A[r * LSTR + c8] = z;
      }
    }
    __syncthreads();
    const int rc = lane & 15, kb = lane >> 4, rb = (lane >> 4) * 4;
    const int col = g * 64 + wid * 16 + rc;
    const bf16x8* ab = reinterpret_cast<const bf16x8*>(A) + rc * (LSTR / 8) + kb;
    const float* wf = rot_w + (size_t)(j * 512 + col) * 512 + kb * 8;
    f32x4 acc = (f32x4){0.f, 0.f, 0.f, 0.f};
#pragma unroll
    for (int ks = 0; ks < 16; ++ks) {
      const float4 w0 = *(const float4*)(wf + ks * 32);
      const float4 w1 = *(const float4*)(wf + ks * 32 + 4);
      acc = MFMA(ab[ks * 4], f8_to_bf(w0, w1), acc);
    }
    const float bv = rot_b[j * 512 + col];
#pragma unroll
    for (int r = 0; r < 4; ++r) {
      const int p = rb + r;
      if (p < 8) pwr_ws[(size_t)(p * 4 + j) * 512 + col] = f2bf(acc[r] + bv);
    }
    return;
  }
  const Job jb = jobs.j[blockIdx.y];
  const int i0 = (blockIdx.x * 256 + tid) * 8;
  if (i0 >= jb.n) return;
  u16* dst = (u16*)(ws + jb.dstoff);
  const float* src = (const float*)jb.base + jb.eoff;
  if (i0 + 8 <= jb.n) {
    const float4 a = *(const float4*)(src + i0);
    const float4 b = *(const float4*)(src + i0 + 4);
    u16 o[8] = {f2bf(a.x), f2bf(a.y), f2bf(a.z), f2bf(a.w),
                f2bf(b.x), f2bf(b.y), f2bf(b.z), f2bf(b.w)};
    int off = i0;
    if (jb.mode == 1) {
      const int col = i0 >> 9, k0 = i0 & 511;
      off = (col >> 4) * 8192 + (k0 >> 5) * 512 + ((k0 >> 3) & 3) * 128 + (col & 15) * 8;
    }
    *(uint4*)(dst + off) = *(uint4*)o;
  } else {
    for (int k = i0; k < jb.n; ++k) dst[k] = f2bf(src[k]);
  }
}

// ---- stage one full layer slice (16KB) for this wave: 16 x 1KB gl_lds
__device__ __forceinline__ void stage_layer(const char* gsrc, u16* dst, int lane) {
#pragma unroll
  for (int s = 0; s < 16; ++s) gl_lds16(gsrc + s * 1024 + lane * 16, dst + s * 512);
}

// ---- pure-LDS GEMM: buf holds the full layer slice. One vmcnt(0) at entry
// (drains this layer's 16 staged loads), then compiler-scheduled ds_read+MFMA.
__device__ __forceinline__ void gemm16(const u16* A, const u16* B, const u16* bias,
                                       int wid, int lane, f32x4& acc) {
  const int rc = lane & 15, kb = lane >> 4;
  asm volatile("s_waitcnt vmcnt(0)" ::: "memory");
  __builtin_amdgcn_sched_barrier(0);
  acc = (f32x4){0.f, 0.f, 0.f, 0.f};
#pragma unroll
  for (int c = 0; c < 16; ++c) {
    const bf16x8 a = *(const bf16x8*)&A[rc * LSTR + c * 32 + kb * 8];
    const bf16x8 b = *(const bf16x8*)&B[c * 512 + kb * 128 + rc * 8];
    acc = MFMA(a, b, acc);
  }
  const float bv = bf2f(bias[wid * 16 + rc]);
#pragma unroll
  for (int r = 0; r < 4; ++r) acc[r] += bv;
}

__device__ __forceinline__ void store_A(u16* A, int cb, int wid, int lane, const f32x4 acc) {
  const int cr = lane & 15, rb = (lane >> 4) * 4;
  const int col = cb + wid * 16 + cr;
#pragma unroll
  for (int r = 0; r < 4; ++r) A[(rb + r) * LSTR + col] = f2bf(acc[r]);
}

__device__ __forceinline__ void add_A(const u16* A, int cb, int wid, int lane, f32x4& acc) {
  const int cr = lane & 15, rb = (lane >> 4) * 4;
  const int col = cb + wid * 16 + cr;
#pragma unroll
  for (int r = 0; r < 4; ++r) acc[r] += bf2f(A[(rb + r) * LSTR + col]);
}

__device__ __forceinline__ void add_glb_f32(const float* g, int cb, int wid, int lane,
                                            f32x4& acc) {
  const int cr = lane & 15, rb = (lane >> 4) * 4;
  const int col = cb + wid * 16 + cr;
#pragma unroll
  for (int r = 0; r < 4; ++r) acc[r] += g[(size_t)(rb + r) * 512 + col];
}

__device__ __forceinline__ void slice_store(u16* act, const u16* A, int r0, int cb, int tid) {
  if (tid < 128) {
    const int r = tid >> 3, c8 = (tid & 7) * 8;
    u32x4 v = *(const u32x4*)&A[r * LSTR + cb + c8];
    st16_cc(act + (size_t)(r0 + r) * 512 + cb + c8, v);
  }
}

__device__ __forceinline__ void load_act(const u16* act, u16* A, int r0, int tid) {
  const u16* base = act + (size_t)r0 * 512;
  const int i0 = tid, i1 = tid + 256, i2 = tid + 512, i3 = tid + 768;
  const void* p0 = base + (i0 >> 6) * 512 + (i0 & 63) * 8;
  const void* p1 = base + (i1 >> 6) * 512 + (i1 & 63) * 8;
  const void* p2 = base + (i2 >> 6) * 512 + (i2 & 63) * 8;
  const void* p3 = base + (i3 >> 6) * 512 + (i3 & 63) * 8;
  u32x4 d0, d1, d2, d3;
  asm volatile(
      "global_load_dwordx4 %0, %4, off sc0 sc1\n\t"
      "global_load_dwordx4 %1, %5, off sc0 sc1\n\t"
      "global_load_dwordx4 %2, %6, off sc0 sc1\n\t"
      "global_load_dwordx4 %3, %7, off sc0 sc1\n\t"
      "s_waitcnt vmcnt(0)"
      : "=&v"(d0), "=&v"(d1), "=&v"(d2), "=&v"(d3)
      : "v"(p0), "v"(p1), "v"(p2), "v"(p3)
      : "memory");
  *(u32x4*)&A[(i0 >> 6) * LSTR + (i0 & 63) * 8] = d0;
  *(u32x4*)&A[(i1 >> 6) * LSTR + (i1 & 63) * 8] = d1;
  *(u32x4*)&A[(i2 >> 6) * LSTR + (i2 & 63) * 8] = d2;
  *(u32x4*)&A[(i3 >> 6) * LSTR + (i3 & 63) * 8] = d3;
}

__device__ __forceinline__ void ln4(u16* A, const u16* g, const u16* b, int wid, int lane) {
#pragma unroll
  for (int rr = 0; rr < 4; ++rr) {
    const int row = wid * 4 + rr;
    float s = 0.f, q = 0.f;
#pragma unroll
    for (int c = lane; c < 512; c += 64) {
      const float v = bf2f(A[row * LSTR + c]);
      s += v; q += v * v;
    }
#pragma unroll
    for (int m = 1; m < 64; m <<= 1) {
      s += __shfl_xor(s, m, 64);
      q += __shfl_xor(q, m, 64);
    }
    const float mu = s * (1.f / 512.f);
    const float rs = rsqrtf(q * (1.f / 512.f) - mu * mu + 1e-5f);
#pragma unroll
    for (int c = lane; c < 512; c += 64) {
      const float v = (bf2f(A[row * LSTR + c]) - mu) * rs * bf2f(g[c]) + bf2f(b[c]);
      A[row * LSTR + c] = f2bf(v);
    }
  }
}

// ---- k_pkv: kk/vv[32][512] f32 from pwr + RAW f32 k_w/v_w. 32 blocks.
__global__ __launch_bounds__(256) void k_pkv(const u16* __restrict__ pwr_ws,
                                             const float* __restrict__ k_w,
                                             const float* __restrict__ k_b,
                                             const float* __restrict__ v_w,
                                             const float* __restrict__ v_b,
                                             float* __restrict__ kk_ws,
                                             float* __restrict__ vv_ws) {
  __shared__ __align__(16) u16 A[32 * LSTR];
  const int tid = threadIdx.x, lane = tid & 63, wid = tid >> 6;
  const int t = blockIdx.x >> 4, g = blockIdx.x & 15;
  for (int idx = tid; idx < 32 * 64; idx += 256) {
    const int r = idx >> 6, c = idx & 63;
    *(uint4*)&A[r * LSTR + c * 8] = ((const uint4*)pwr_ws)[r * 64 + c];
  }
  __syncthreads();
  const float* W = t ? v_w : k_w;
  const float* Bb = t ? v_b : k_b;
  float* out = t ? vv_ws : kk_ws;
  const int rc = lane & 15, kb = lane >> 4, rb = (lane >> 4) * 4;
  const int rowt = wid >> 1;
  const int col = g * 32 + (wid & 1) * 16 + rc;
  const bf16x8* ab = reinterpret_cast<const bf16x8*>(A) + (rowt * 16 + rc) * (LSTR / 8) + kb;
  const float* wf = W + (size_t)col * 512 + kb * 8;
  f32x4 acc = (f32x4){0.f, 0.f, 0.f, 0.f};
#pragma unroll
  for (int ks = 0; ks < 16; ++ks) {
    const float4 w0 = *(const float4*)(wf + ks * 32);
    const float4 w1 = *(const float4*)(wf + ks * 32 + 4);
    acc = MFMA(ab[ks * 4], f8_to_bf(w0, w1), acc);
  }
  const float bv = Bb[col];
#pragma unroll
  for (int r = 0; r < 4; ++r)
    out[(size_t)(rowt * 16 + rb + r) * 512 + col] = acc[r] + bv;
}

// ---- main: 256 blocks (32 row-groups x 8 col-blocks of 64 cols) x 256 thr.
// Per-wave whole-layer double buffer (2 x 16KB); one vmcnt(0) per layer.
__global__ __launch_bounds__(256) void k_main(
    const float* __restrict__ state32, const float* __restrict__ mem32,
    const int* __restrict__ queue, char* __restrict__ ws,
    const float* __restrict__ kk_ws, const float* __restrict__ vv_ws,
    float* __restrict__ out_pol, float* __restrict__ out_val) {
  __shared__ __align__(16) u16 A[16 * LSTR];
  __shared__ __align__(16) u16 WB[4 * 2 * 8192];  // 4 waves x 2 bufs x 16KB
  __shared__ int piece_s[16];
  __shared__ int qs_s;
  const int tid = threadIdx.x;
  const int lane = tid & 63, wid = tid >> 6;
  const int idx = blockIdx.x;
  const int xcd = idx & 7, bc = (idx >> 3) & 7, hi = idx >> 6;
  const int br = hi * 8 + xcd;
  const int r0 = br * 16, cb = bc * 64;
  u16* wb0 = &WB[wid * 16384];
  u16* wb1 = wb0 + 8192;
  u16* act = (u16*)(ws + WS_ACT);
  int* grp = (int*)(ws + WS_CTR) + br * 32;
  const int wofs = bc * 65536 + wid * 16384;  // this wave's 16KB slice in each weight

  const u16* a0v_b = (const u16*)(ws + WS_A0VB) + cb;
  const u16* a0o_b = (const u16*)(ws + WS_A0OB) + cb;
  const u16* q_b   = (const u16*)(ws + WS_QB) + cb;
  const u16* qkv_b = (const u16*)(ws + WS_QKVB) + cb;
  const u16* que_b = (const u16*)(ws + WS_QUEB) + cb;
  const u16* a1v_b = (const u16*)(ws + WS_A1VB) + cb;
  const u16* a1o_b = (const u16*)(ws + WS_A1OB) + cb;
  const u16* val_b = (const u16*)(ws + WS_VALB) + cb;
  const u16* pol_w = (const u16*)(ws + WS_POL);
  const u16* pol_b = (const u16*)(ws + WS_POLB);
  const u16* an_g = (const u16*)(ws + WS_ANG);  const u16* an_b = (const u16*)(ws + WS_ANB);
  const u16* fn_g = (const u16*)(ws + WS_FNG);  const u16* fn_b = (const u16*)(ws + WS_FNB);

  // prologue: stage L1 slice into buf0, convert state rows, queue probe
  stage_layer(ws + WS_A0V + wofs, wb0, lane);
  for (int i = tid; i < 1024; i += 256) {
    const int r = i >> 6, c8 = (i & 63) * 8;
    const float* src = state32 + (size_t)(r0 + r) * 512 + c8;
    const float4 a = *(const float4*)src;
    const float4 b = *(const float4*)(src + 4);
    bf16x8 v = f8_to_bf(a, b);
    *(bf16x8*)&A[r * LSTR + c8] = v;
  }
  if (tid == 0) {
    int odd = 0;
    for (int i = 1; i < 128; i += 2) odd += (queue[i] != 0);
    qs_s = (odd == 0) ? 2 : 1;
  }
  __syncthreads();
  if (tid < 16) piece_s[tid] = queue[(size_t)(r0 + tid) * 5 * qs_s] & 7;

  f32x4 acc, res;
  // L1: v0 = state @ a0v^T    [buf0]
  gemm16(A, wb0, a0v_b, wid, lane, acc);
  __syncthreads();
  store_A(A, cb, wid, lane, acc);
  __syncthreads();
  slice_store(act, A, r0, cb, tid);
  stage_layer(ws + WS_A0O + wofs, wb1, lane);
  gridbar(grp, 8 * 1, tid);
  load_act(act, A, r0, tid);
  __syncthreads();
  // L2: s0 = v0 @ a0o^T (residual)   [buf1]
  gemm16(A, wb1, a0o_b, wid, lane, acc);
  res = acc;
  __syncthreads();
  store_A(A, cb, wid, lane, acc);
  __syncthreads();
  slice_store(act, A, r0, cb, tid);
  stage_layer(ws + WS_QW + wofs, wb0, lane);
  gridbar(grp, 8 * 2, tid);
  load_act(act, A, r0, tid);
  __syncthreads();
  // L3: qv = s0 @ q_w^T  [buf0]; attention head h=bc (col-local)
  gemm16(A, wb0, q_b, wid, lane, acc);
  __syncthreads();
  store_A(A, cb, wid, lane, acc);
  __syncthreads();
  if (tid < 16) {
    const int r = tid, h = bc;
    const int p = piece_s[r];
    const u16* qrow = &A[r * LSTR + h * 64];
    const float* kkp = kk_ws + (size_t)(p * 4) * 512 + h * 64;
    const float* vvp = vv_ws + (size_t)(p * 4) * 512 + h * 64;
    float lg[4];
#pragma unroll
    for (int jj = 0; jj < 4; ++jj) {
      float s = 0.f;
      const float* kj = kkp + jj * 512;
#pragma unroll
      for (int d = 0; d < 64; d += 4) {
        const float4 kv = *(const float4*)(kj + d);
        s += bf2f(qrow[d]) * kv.x + bf2f(qrow[d + 1]) * kv.y + bf2f(qrow[d + 2]) * kv.z +
             bf2f(qrow[d + 3]) * kv.w;
      }
      lg[jj] = s * 0.125f;
    }
    const float m = fmaxf(fmaxf(lg[0], lg[1]), fmaxf(lg[2], lg[3]));
    float e0 = __expf(lg[0] - m), e1 = __expf(lg[1] - m);
    float e2 = __expf(lg[2] - m), e3 = __expf(lg[3] - m);
    const float inv = 1.f / (e0 + e1 + e2 + e3);
    e0 *= inv; e1 *= inv; e2 *= inv; e3 *= inv;
    u16* orow = &A[r * LSTR + h * 64];
#pragma unroll
    for (int d = 0; d < 64; d += 4) {
      const float4 v0 = *(const float4*)(vvp + 0 * 512 + d);
      const float4 v1 = *(const float4*)(vvp + 1 * 512 + d);
      const float4 v2 = *(const float4*)(vvp + 2 * 512 + d);
      const float4 v3 = *(const float4*)(vvp + 3 * 512 + d);
      orow[d + 0] = f2bf(e0 * v0.x + e1 * v1.x + e2 * v2.x + e3 * v3.x);
      orow[d + 1] = f2bf(e0 * v0.y + e1 * v1.y + e2 * v2.y + e3 * v3.y);
      orow[d + 2] = f2bf(e0 * v0.z + e1 * v1.z + e2 * v2.z + e3 * v3.z);
      orow[d + 3] = f2bf(e0 * v0.w + e1 * v1.w + e2 * v2.w + e3 * v3.w);
    }
  }
  __syncthreads();
  slice_store(act, A, r0, cb, tid);
  stage_layer(ws + WS_QKV + wofs, wb1, lane);
  gridbar(grp, 8 * 3, tid);
  load_act(act, A, r0, tid);
  __syncthreads();
  // L4: x1 = s0(res) + attn @ qkv^T   [buf1]
  gemm16(A, wb1, qkv_b, wid, lane, acc);
  acc += res;
  __syncthreads();
  store_A(A, cb, wid, lane, acc);
  __syncthreads();
  slice_store(act, A, r0, cb, tid);
  stage_layer(ws + WS_QUE + wofs, wb0, lane);
  gridbar(grp, 8 * 4, tid);
  load_act(act, A, r0, tid);
  __syncthreads();
  ln4(A, an_g, an_b, wid, lane);  // s1
  __syncthreads();
  // L5: x2 = s1 + s1 @ que_w^T   [buf0]
  gemm16(A, wb0, que_b, wid, lane, acc);
  add_A(A, cb, wid, lane, acc);
  __syncthreads();
  store_A(A, cb, wid, lane, acc);
  __syncthreads();
  slice_store(act, A, r0, cb, tid);
  stage_layer(ws + WS_A1V + wofs, wb1, lane);
  gridbar(grp, 8 * 5, tid);
  load_act(act, A, r0, tid);
  __syncthreads();
  ln4(A, fn_g, fn_b, wid, lane);  // s2
  __syncthreads();
  // L6: v1 = s2 @ a1v^T   [buf1]
  gemm16(A, wb1, a1v_b, wid, lane, acc);
  __syncthreads();
  store_A(A, cb, wid, lane, acc);
  __syncthreads();
  slice_store(act, A, r0, cb, tid);
  stage_layer(ws + WS_A1O + wofs, wb0, lane);
  gridbar(grp, 8 * 6, tid);
  load_act(act, A, r0, tid);
  __syncthreads();
  // L7: xo = v1 @ a1o^T + memory   [buf0]
  gemm16(A, wb0, a1o_b, wid, lane, acc);
  add_glb_f32(mem32 + (size_t)r0 * 512, cb, wid, lane, acc);
  __syncthreads();
  store_A(A, cb, wid, lane, acc);
  __syncthreads();
  slice_store(act, A, r0, cb, tid);
  stage_layer(ws + WS_VAL + wofs, wb1, lane);
  gridbar(grp, 8 * 7, tid);
  load_act(act, A, r0, tid);
  __syncthreads();
  // L8: val = xo @ val_w^T -> out (f32)   [buf1]
  gemm16(A, wb1, val_b, wid, lane, acc);
  {
    const int cr = lane & 15, rb = (lane >> 4) * 4;
    const int col = cb + wid * 16 + cr;
#pragma unroll
    for (int r = 0; r < 4; ++r) out_val[(size_t)(r0 + rb + r) * 512 + col] = acc[r];
  }
  // L9: pol (10 cols) - bc==0 blocks, wave 0 (xo full rows in A)
  if (bc == 0 && wid == 0) {
    const int rc = lane & 15, kb = lane >> 4;
    const int wrow = rc < 10 ? rc : 0;
    const bf16x8* ab = reinterpret_cast<const bf16x8*>(A) + rc * (LSTR / 8) + kb;
    const bf16x8* wbp = reinterpret_cast<const bf16x8*>(pol_w) + wrow * 64 + kb;
    f32x4 pa = (f32x4){0.f, 0.f, 0.f, 0.f};
#pragma unroll
    for (int ks = 0; ks < 16; ++ks) pa = MFMA(ab[ks * 4], wbp[ks * 4], pa);
    if (rc < 10) {
      const float bv = bf2f(pol_b[rc]);
      const int rb = (lane >> 4) * 4;
#pragma unroll
      for (int r = 0; r < 4; ++r) out_pol[(size_t)(r0 + rb + r) * 10 + rc] = pa[r] + bv;
    }
  }
}

extern "C" void kernel_launch(void* const* d_in, const int* in_sizes, int n_in, void* d_out,
                              int out_size, void* d_ws, size_t ws_size, hipStream_t stream) {
  (void)in_sizes; (void)n_in; (void)out_size; (void)ws_size;
  char* ws = (char*)d_ws;

  Jobs jobs;
  int ji = 0;
  auto add = [&](int idx, int eoff, int n, int off, int mode) {
    jobs.j[ji].base = d_in[idx]; jobs.j[ji].eoff = eoff; jobs.j[ji].n = n;
    jobs.j[ji].dstoff = off; jobs.j[ji].mode = mode; ++ji;
  };
  add(38, 524288, 262144, WS_A0V, 1);   // a0_in_w rows [1024:1536] (v-slice)
  add(40, 0, 262144, WS_A0O, 1);
  add(12, 0, 262144, WS_QW, 1);
  add(18, 0, 262144, WS_QKV, 1);
  add(20, 0, 262144, WS_QUE, 1);
  add(42, 524288, 262144, WS_A1V, 1);   // a1_in_w rows [1024:1536]
  add(44, 0, 262144, WS_A1O, 1);
  add(48, 0, 262144, WS_VAL, 1);
  add(46, 0, 5120, WS_POL, 0);
  add(39, 1024, 512, WS_A0VB, 0);
  add(41, 0, 512, WS_A0OB, 0);
  add(13, 0, 512, WS_QB, 0);
  add(19, 0, 512, WS_QKVB, 0);
  add(21, 0, 512, WS_QUEB, 0);
  add(43, 1024, 512, WS_A1VB, 0);
  add(45, 0, 512, WS_A1OB, 0);
  add(49, 0, 512, WS_VALB, 0);
  add(22, 0, 512, WS_ANG, 0);
  add(23, 0, 512, WS_ANB, 0);
  add(24, 0, 512, WS_FNG, 0);
  add(25, 0, 512, WS_FNB, 0);
  add(47, 0, 10, WS_POLB, 0);

  k_convert<<<dim3(128, NJOBS + 1), dim3(256), 0, stream>>>(
      jobs, ws, (const float*)d_in[9], (const float*)d_in[10], (const float*)d_in[11],
      (u16*)(ws + WS_PWR));
  k_pkv<<<dim3(32), dim3(256), 0, stream>>>((const u16*)(ws + WS_PWR), (const float*)d_in[14],
                                            (const float*)d_in[15], (const float*)d_in[16],
                                            (const float*)d_in[17], (float*)(ws + WS_KK),
                                            (float*)(ws + WS_VV));

  float* out_pol = (float*)d_out;
  float* out_val = out_pol + 512 * 10;
  k_main<<<dim3(256), dim3(256), 0, stream>>>(
      (const float*)d_in[3], (const float*)d_in[4], (const int*)d_in[1], ws,
      (const float*)(ws + WS_KK), (const float*)(ws + WS_VV), out_pol, out_val);
}